// Round 5
// baseline (167.787 us; speedup 1.0000x reference)
//
#include <hip/hip_runtime.h>
#include <stdint.h>

typedef __attribute__((ext_vector_type(4))) float f32x4;
typedef __attribute__((ext_vector_type(8))) __bf16 bf16v8;
typedef __attribute__((ext_vector_type(8))) unsigned short u16x8;
typedef __attribute__((ext_vector_type(4))) unsigned short u16x4;
typedef unsigned short u16;

#define AS1 __attribute__((address_space(1)))
#define AS3 __attribute__((address_space(3)))

__device__ __forceinline__ u16 f2b(float f) {
  union { __bf16 h; u16 u; } c; c.h = (__bf16)f; return c.u;
}

__device__ __forceinline__ f32x4 mfma16(bf16v8 a, bf16v8 b, f32x4 c) {
  return __builtin_amdgcn_mfma_f32_16x16x32_bf16(a, b, c, 0, 0, 0);
}

__device__ __forceinline__ void gl_lds16(const void* g, void* l) {
  __builtin_amdgcn_global_load_lds((AS1 void*)g, (AS3 void*)l, 16, 0, 0);
}

// ---------------------------------------------------------------- pack x ----
__global__ __launch_bounds__(256) void pack_x_kernel(
    const float* __restrict__ x, u16* __restrict__ xb, int n8) {
  int i = blockIdx.x * 256 + threadIdx.x;
  if (i >= n8) return;
  const f32x4* p = (const f32x4*)(x + (size_t)i * 8);
  f32x4 a = p[0], b = p[1];
  u16x8 o;
  o[0] = f2b(a[0]); o[1] = f2b(a[1]); o[2] = f2b(a[2]); o[3] = f2b(a[3]);
  o[4] = f2b(b[0]); o[5] = f2b(b[1]); o[6] = f2b(b[2]); o[7] = f2b(b[3]);
  *(u16x8*)(xb + (size_t)i * 8) = o;
}

// --------------------------------------------------------- pack weights ----
// out[n*out_ns + b*out_rs + a] = bf16(scale * in[n*in_ns + a*in_rs + b])
__global__ __launch_bounds__(256) void pack_w_kernel(
    const float* __restrict__ in, u16* __restrict__ out,
    int in_ns, int in_rs, int out_ns, int out_rs, float scale) {
  __shared__ float t[64][65];
  const int n = blockIdx.z;
  const int a0 = blockIdx.x * 64, b0 = blockIdx.y * 64;
  const int c = threadIdx.x & 63, w = threadIdx.x >> 6;
  const float* ip = in + (size_t)n * in_ns;
#pragma unroll
  for (int i = 0; i < 16; ++i) {
    int r = i * 4 + w;
    t[r][c] = ip[(size_t)(a0 + r) * in_rs + (b0 + c)];
  }
  __syncthreads();
  u16* op = out + (size_t)n * out_ns;
#pragma unroll
  for (int i = 0; i < 16; ++i) {
    int r = i * 4 + w;
    op[(size_t)(b0 + r) * out_rs + (a0 + c)] = f2b(t[c][r] * scale);
  }
}

// ------------------------------------------------------------- pack bias ----
// bcat[0..767] = bq * sq ; bcat[768..1535] = bk
__global__ __launch_bounds__(256) void pack_bias_kernel(
    const float* __restrict__ bq, const float* __restrict__ bk,
    float* __restrict__ o, float sq) {
  int i = blockIdx.x * 256 + threadIdx.x;
  if (i < 768) o[i] = bq[i] * sq;
  else if (i < 1536) o[i] = bk[i - 768];
}

// ------------------------------------------------------------------ GEMM ----
// C[m][col] = (sum_k A[m][k]*Bt[col][k] + bias[BIASROW? m : col]) * scale
// A: [M][768] bf16, Bt: [Ncols][768] bf16.  Grid (M/128, Ncols/128), 256 thr.
template <int OUTF32, int BIASROW>
__global__ __launch_bounds__(256, 2) void gemm_bt(
    const u16* __restrict__ A, const u16* __restrict__ Bt,
    void* __restrict__ Cv, const float* __restrict__ bias, float scale, int N) {
  constexpr int K = 768;
  __shared__ u16 lA[2][128 * 32];
  __shared__ u16 lB[2][128 * 32];

  const int tid = threadIdx.x;
  const int lane = tid & 63, wid = tid >> 6;
  const int wr = wid >> 1, wc = wid & 1;
  const int g = lane >> 4, l16 = lane & 15;
  const int m0 = blockIdx.x * 128, n0 = blockIdx.y * 128;

  const int srow = tid >> 2;
  const int scol = (tid & 3) * 16;

  f32x4 acc[4][4];
#pragma unroll
  for (int i = 0; i < 4; ++i)
#pragma unroll
    for (int j = 0; j < 4; ++j) acc[i][j] = (f32x4)0.f;

  const char* Ab = (const char*)(A + (size_t)m0 * K);
  const char* Bb = (const char*)(Bt + (size_t)n0 * K);
  char* lAb = (char*)&lA[0][0];
  char* lBb = (char*)&lB[0][0];

#define STAGE(buf, kt)                                                          \
  do {                                                                          \
    int kb = (kt) * 64;                                                         \
    gl_lds16(Ab + (size_t)srow * 1536 + kb + scol,                              \
             lAb + (buf) * 8192 + wid * 1024);                                  \
    gl_lds16(Bb + (size_t)srow * 1536 + kb + scol,                              \
             lBb + (buf) * 8192 + wid * 1024);                                  \
    gl_lds16(Ab + (size_t)(64 + srow) * 1536 + kb + scol,                       \
             lAb + (buf) * 8192 + 4096 + wid * 1024);                           \
    gl_lds16(Bb + (size_t)(64 + srow) * 1536 + kb + scol,                       \
             lBb + (buf) * 8192 + 4096 + wid * 1024);                           \
  } while (0)

  STAGE(0, 0);
  __syncthreads();

  for (int kt = 0; kt < 24; ++kt) {
    const int cur = kt & 1;
    if (kt + 1 < 24) STAGE(cur ^ 1, kt + 1);
    bf16v8 af[4], bfv[4];
#pragma unroll
    for (int i = 0; i < 4; ++i) {
      af[i]  = *(const bf16v8*)&lA[cur][(wr * 64 + i * 16 + l16) * 32 + g * 8];
      bfv[i] = *(const bf16v8*)&lB[cur][(wc * 64 + i * 16 + l16) * 32 + g * 8];
    }
#pragma unroll
    for (int i = 0; i < 4; ++i)
#pragma unroll
      for (int j = 0; j < 4; ++j)
        acc[i][j] = mfma16(af[i], bfv[j], acc[i][j]);
    __syncthreads();
  }
#undef STAGE

  const int row0 = m0 + wr * 64, col0 = n0 + wc * 64;
#pragma unroll
  for (int j = 0; j < 4; ++j) {
    const int col = col0 + j * 16 + l16;
    const float bcol = BIASROW ? 0.f : bias[col];
#pragma unroll
    for (int i = 0; i < 4; ++i) {
#pragma unroll
      for (int r = 0; r < 4; ++r) {
        const int row = row0 + i * 16 + g * 4 + r;
        const float bv = BIASROW ? bias[row] : bcol;
        const float v = (acc[i][j][r] + bv) * scale;
        if (OUTF32) ((float*)Cv)[(size_t)row * N + col] = v;
        else        ((u16*)Cv)[(size_t)row * N + col] = f2b(v);
      }
    }
  }
}

// ----------------------------------------------------------- flash attn ----
// QK: [B*S][1536] bf16 (Q at cols n*64.., K at 768 + n*64..); Q pre-scaled by
// log2e/8 (exp2 softmax domain).  Vt: [768][8192] bf16 (row n*64+h, col
// b*1024+s).  Z: [B*S][768] bf16.
// Grid: 768 linear blocks, 256 threads, 4 independent waves (NO barriers).
// Block id: xs=id&7 keeps all blocks of a head on one XCD (12 heads x 256KB
// = 3MB < 4MB L2 -> K/V fragment loads are L2 hits).  Block x covers qtiles
// {x, 15-x, 16+x, 31-x}: exactly 34 chunk-waves for every block; wave->qtile
// rotated by x so heavy waves spread across SIMDs.
// Swapped QK^T: S^T = mfma(K, Q) so softmax is lane-local; LDS only for the
// per-wave P re-layout (18.4 KB/block).
__global__ __launch_bounds__(256) void flash4_kernel(
    const u16* __restrict__ QK, const u16* __restrict__ Vt,
    u16* __restrict__ Z) {
  __shared__ u16 lP[4][32 * 72];
  const int tid = threadIdx.x;
  const int lane = tid & 63, wid = tid >> 6;
  const int g = lane >> 4, l16 = lane & 15;

  const int id = blockIdx.x;
  const int xs = id & 7;
  const int rest = id >> 3;                  // 0..95
  const int x = rest & 7;                    // balanced qtile-set selector
  const int head = xs + ((rest >> 3) << 3);  // head%8 == xs (XCD grouping)
  const int b = head / 12, n = head % 12;

  const int k4 = (wid + x) & 3;              // rotate heavy wave across SIMDs
  const int qtile = (k4 & 1) ? ((k4 & 2) ? 31 - x : 15 - x)
                             : ((k4 & 2) ? 16 + x : x);
  const int qw = qtile << 5;
  const int nch = (qtile >> 1) + 1;

  const u16* Qh = QK + (size_t)b * 1024 * 1536 + n * 64;
  const u16* Kh = Qh + 768;
  const u16* Vh = Vt + (size_t)n * 64 * 8192 + b * 1024;
  u16* Zh = Z + (size_t)b * 1024 * 768 + n * 64;
  u16* myP = &lP[wid][0];

  // Q fragments (B-operand)
  bf16v8 qf[2][2];
#pragma unroll
  for (int qt = 0; qt < 2; ++qt)
#pragma unroll
    for (int kk = 0; kk < 2; ++kk)
      qf[qt][kk] = *(const bf16v8*)(Qh + (size_t)(qw + qt * 16 + l16) * 1536 +
                                    kk * 32 + g * 8);

  f32x4 po[2][4];
#pragma unroll
  for (int qt = 0; qt < 2; ++qt)
#pragma unroll
    for (int ht = 0; ht < 4; ++ht) po[qt][ht] = (f32x4)0.f;
  float m[2] = {-3e38f, -3e38f};
  float l[2] = {0.f, 0.f};

  for (int c = 0; c < nch; ++c) {
    const int kv0 = c << 6;
    // K fragments (A-operand) from global (L2-resident)
    bf16v8 kf[4][2];
#pragma unroll
    for (int kvt = 0; kvt < 4; ++kvt)
#pragma unroll
      for (int kk = 0; kk < 2; ++kk)
        kf[kvt][kk] = *(const bf16v8*)(Kh +
            (size_t)(kv0 + kvt * 16 + l16) * 1536 + kk * 32 + g * 8);
    // V^T fragments (B-operand) — issue early; latency hides under QK+softmax
    bf16v8 vf[4][2];
#pragma unroll
    for (int ht = 0; ht < 4; ++ht)
#pragma unroll
      for (int kk = 0; kk < 2; ++kk)
        vf[ht][kk] = *(const bf16v8*)(Vh + (size_t)(ht * 16 + l16) * 8192 +
                                      kv0 + kk * 32 + g * 8);
    // S^T[kv][q] (log2 domain)
    f32x4 s[4][2];
#pragma unroll
    for (int kvt = 0; kvt < 4; ++kvt)
#pragma unroll
      for (int qt = 0; qt < 2; ++qt) {
        f32x4 a = (f32x4)0.f;
        a = mfma16(kf[kvt][0], qf[qt][0], a);
        a = mfma16(kf[kvt][1], qf[qt][1], a);
        s[kvt][qt] = a;
      }
    if (c == nch - 1) {  // causal mask: only the last chunk ever needs it
#pragma unroll
      for (int kvt = 0; kvt < 4; ++kvt) {
        const int kv = kv0 + kvt * 16 + g * 4;
#pragma unroll
        for (int qt = 0; qt < 2; ++qt) {
          const int qq = qw + qt * 16 + l16;
#pragma unroll
          for (int r = 0; r < 4; ++r)
            if (kv + r > qq) s[kvt][qt][r] = -3e38f;
        }
      }
    }
    // online softmax: q-row = l16 is lane-local over kv
#pragma unroll
    for (int qt = 0; qt < 2; ++qt) {
      float cm = s[0][qt][0];
#pragma unroll
      for (int kvt = 0; kvt < 4; ++kvt)
#pragma unroll
        for (int r = 0; r < 4; ++r) cm = fmaxf(cm, s[kvt][qt][r]);
      cm = fmaxf(cm, __shfl_xor(cm, 16));
      cm = fmaxf(cm, __shfl_xor(cm, 32));
      const float mn = fmaxf(m[qt], cm);
      const float scl = exp2f(m[qt] - mn);
      m[qt] = mn;
      float rs = 0.f;
#pragma unroll
      for (int kvt = 0; kvt < 4; ++kvt) {
        u16x4 pw;
#pragma unroll
        for (int r = 0; r < 4; ++r) {
          const float p = exp2f(s[kvt][qt][r] - mn);
          rs += p;
          pw[r] = f2b(p);
        }
        *(u16x4*)&myP[(qt * 16 + l16) * 72 + kvt * 16 + g * 4] = pw;
      }
      rs += __shfl_xor(rs, 16);
      rs += __shfl_xor(rs, 32);
      l[qt] = l[qt] * scl + rs;
#pragma unroll
      for (int r = 0; r < 4; ++r) {
        const float sr = __shfl(scl, g * 4 + r);
#pragma unroll
        for (int ht = 0; ht < 4; ++ht) po[qt][ht][r] *= sr;
      }
    }
    // P fragments (A-operand) from wave-private LDS
    bf16v8 pa[2][2];
#pragma unroll
    for (int mt = 0; mt < 2; ++mt)
#pragma unroll
      for (int kk = 0; kk < 2; ++kk)
        pa[mt][kk] = *(const bf16v8*)&myP[(mt * 16 + l16) * 72 +
                                          kk * 32 + g * 8];
#pragma unroll
    for (int ht = 0; ht < 4; ++ht)
#pragma unroll
      for (int mt = 0; mt < 2; ++mt) {
        po[mt][ht] = mfma16(pa[mt][0], vf[ht][0], po[mt][ht]);
        po[mt][ht] = mfma16(pa[mt][1], vf[ht][1], po[mt][ht]);
      }
  }

  // epilogue: broadcast l to accumulator layout, divide, store
#pragma unroll
  for (int qt = 0; qt < 2; ++qt) {
#pragma unroll
    for (int r = 0; r < 4; ++r) {
      const float lr = __shfl(l[qt], g * 4 + r);
      const float inv = 1.f / lr;
      const int qq = qw + qt * 16 + g * 4 + r;
#pragma unroll
      for (int ht = 0; ht < 4; ++ht)
        Zh[(size_t)qq * 768 + ht * 16 + l16] = f2b(po[qt][ht][r] * inv);
    }
  }
}

// ---------------------------------------------------------------- launch ----
extern "C" void kernel_launch(void* const* d_in, const int* in_sizes, int n_in,
                              void* d_out, int out_size, void* d_ws,
                              size_t ws_size, hipStream_t stream) {
  const float* x  = (const float*)d_in[0];
  const float* wq = (const float*)d_in[1];
  const float* wk = (const float*)d_in[2];
  const float* wv = (const float*)d_in[3];
  const float* wo = (const float*)d_in[4];
  const float* bq = (const float*)d_in[5];
  const float* bk = (const float*)d_in[6];
  const float* bv = (const float*)d_in[7];
  const float* bo = (const float*)d_in[8];
  float* out = (float*)d_out;

  const float sq = 0.18033688011112042f;  // log2(e) / sqrt(64)

  char* ws = (char*)d_ws;
  u16* Xb   = (u16*)ws; ws += 12582912;   // [8192][768] bf16
  u16* BtQK = (u16*)ws; ws += 2359296;    // [1536][768] bf16: WqT*sq | WkT
  u16* WvT  = (u16*)ws; ws += 1179648;    // [768][768]
  u16* WoT  = (u16*)ws; ws += 1179648;    // [768][768]
  float* bc = (float*)ws; ws += 6144;     // [1536] fp32: bq*sq | bk
  u16* QKb  = (u16*)ws; ws += 25165824;   // [8192][1536] (Q | K)
  u16* Vtb  = (u16*)ws; ws += 12582912;   // [768][8192]  (V transposed)
  u16* Zb   = (u16*)ws; ws += 12582912;   // [8192][768]

  pack_x_kernel<<<3072, 256, 0, stream>>>(x, Xb, 786432);
  // W_Q (scaled by log2e/8) and W_K -> adjacent B^T blocks
  pack_w_kernel<<<dim3(12, 1, 12), 256, 0, stream>>>(wq, BtQK, 49152, 64,
                                                     49152, 768, sq);
  pack_w_kernel<<<dim3(12, 1, 12), 256, 0, stream>>>(wk, BtQK + 589824, 49152,
                                                     64, 49152, 768, 1.0f);
  pack_w_kernel<<<dim3(12, 1, 12), 256, 0, stream>>>(wv, WvT, 49152, 64,
                                                     49152, 768, 1.0f);
  pack_w_kernel<<<dim3(1, 12, 12), 256, 0, stream>>>(wo, WoT, 49152, 768,
                                                     64, 768, 1.0f);
  pack_bias_kernel<<<6, 256, 0, stream>>>(bq, bk, bc, sq);

  // fused Q|K projection: [8192][1536]
  gemm_bt<0, 0><<<dim3(64, 12), 256, 0, stream>>>(Xb, BtQK, QKb, bc, 1.0f,
                                                  1536);
  // V^T = (Wv^T) . X^T directly: A = WvT [768][768], Bt = Xb [8192][768]
  gemm_bt<0, 1><<<dim3(6, 64), 256, 0, stream>>>(WvT, Xb, Vtb, bv, 1.0f, 8192);

  flash4_kernel<<<dim3(768), 256, 0, stream>>>(QKb, Vtb, Zb);

  gemm_bt<1, 0><<<dim3(64, 6), 256, 0, stream>>>(Zb, WoT, out, bo, 1.0f, 768);
}

// Round 6
// 148.451 us; speedup vs baseline: 1.1302x; 1.1302x over previous
//
#include <hip/hip_runtime.h>
#include <stdint.h>

typedef __attribute__((ext_vector_type(4))) float f32x4;
typedef __attribute__((ext_vector_type(8))) __bf16 bf16v8;
typedef __attribute__((ext_vector_type(8))) unsigned short u16x8;
typedef __attribute__((ext_vector_type(4))) unsigned short u16x4;
typedef unsigned short u16;

#define AS1 __attribute__((address_space(1)))
#define AS3 __attribute__((address_space(3)))

__device__ __forceinline__ u16 f2b(float f) {
  union { __bf16 h; u16 u; } c; c.h = (__bf16)f; return c.u;
}

__device__ __forceinline__ f32x4 mfma16(bf16v8 a, bf16v8 b, f32x4 c) {
  return __builtin_amdgcn_mfma_f32_16x16x32_bf16(a, b, c, 0, 0, 0);
}

__device__ __forceinline__ void gl_lds16(const void* g, void* l) {
  __builtin_amdgcn_global_load_lds((AS1 void*)g, (AS3 void*)l, 16, 0, 0);
}

// ---------------------------------------------------------------- pack x ----
__global__ __launch_bounds__(256) void pack_x_kernel(
    const float* __restrict__ x, u16* __restrict__ xb, int n8) {
  int i = blockIdx.x * 256 + threadIdx.x;
  if (i >= n8) return;
  const f32x4* p = (const f32x4*)(x + (size_t)i * 8);
  f32x4 a = p[0], b = p[1];
  u16x8 o;
  o[0] = f2b(a[0]); o[1] = f2b(a[1]); o[2] = f2b(a[2]); o[3] = f2b(a[3]);
  o[4] = f2b(b[0]); o[5] = f2b(b[1]); o[6] = f2b(b[2]); o[7] = f2b(b[3]);
  *(u16x8*)(xb + (size_t)i * 8) = o;
}

// --------------------------------------------------------- pack weights ----
// out[n*out_ns + b*out_rs + a] = bf16(scale * in[n*in_ns + a*in_rs + b])
__global__ __launch_bounds__(256) void pack_w_kernel(
    const float* __restrict__ in, u16* __restrict__ out,
    int in_ns, int in_rs, int out_ns, int out_rs, float scale) {
  __shared__ float t[64][65];
  const int n = blockIdx.z;
  const int a0 = blockIdx.x * 64, b0 = blockIdx.y * 64;
  const int c = threadIdx.x & 63, w = threadIdx.x >> 6;
  const float* ip = in + (size_t)n * in_ns;
#pragma unroll
  for (int i = 0; i < 16; ++i) {
    int r = i * 4 + w;
    t[r][c] = ip[(size_t)(a0 + r) * in_rs + (b0 + c)];
  }
  __syncthreads();
  u16* op = out + (size_t)n * out_ns;
#pragma unroll
  for (int i = 0; i < 16; ++i) {
    int r = i * 4 + w;
    op[(size_t)(b0 + r) * out_rs + (a0 + c)] = f2b(t[c][r] * scale);
  }
}

// ------------------------------------------------------------- pack bias ----
__global__ __launch_bounds__(256) void pack_bias_kernel(
    const float* __restrict__ bq, const float* __restrict__ bk,
    float* __restrict__ o, float sq) {
  int i = blockIdx.x * 256 + threadIdx.x;
  if (i < 768) o[i] = bq[i] * sq;
  else if (i < 1536) o[i] = bk[i - 768];
}

// ------------------------------------------------------------------ GEMM ----
// C[m][col] = (sum_k A[m][k]*Bt[col][k] + bias[BIASROW? m : col]) * scale
template <int OUTF32, int BIASROW>
__global__ __launch_bounds__(256, 2) void gemm_bt(
    const u16* __restrict__ A, const u16* __restrict__ Bt,
    void* __restrict__ Cv, const float* __restrict__ bias, float scale, int N) {
  constexpr int K = 768;
  __shared__ u16 lA[2][128 * 32];
  __shared__ u16 lB[2][128 * 32];

  const int tid = threadIdx.x;
  const int lane = tid & 63, wid = tid >> 6;
  const int wr = wid >> 1, wc = wid & 1;
  const int g = lane >> 4, l16 = lane & 15;
  const int m0 = blockIdx.x * 128, n0 = blockIdx.y * 128;

  const int srow = tid >> 2;
  const int scol = (tid & 3) * 16;

  f32x4 acc[4][4];
#pragma unroll
  for (int i = 0; i < 4; ++i)
#pragma unroll
    for (int j = 0; j < 4; ++j) acc[i][j] = (f32x4)0.f;

  const char* Ab = (const char*)(A + (size_t)m0 * K);
  const char* Bb = (const char*)(Bt + (size_t)n0 * K);
  char* lAb = (char*)&lA[0][0];
  char* lBb = (char*)&lB[0][0];

#define STAGE(buf, kt)                                                          \
  do {                                                                          \
    int kb = (kt) * 64;                                                         \
    gl_lds16(Ab + (size_t)srow * 1536 + kb + scol,                              \
             lAb + (buf) * 8192 + wid * 1024);                                  \
    gl_lds16(Bb + (size_t)srow * 1536 + kb + scol,                              \
             lBb + (buf) * 8192 + wid * 1024);                                  \
    gl_lds16(Ab + (size_t)(64 + srow) * 1536 + kb + scol,                       \
             lAb + (buf) * 8192 + 4096 + wid * 1024);                           \
    gl_lds16(Bb + (size_t)(64 + srow) * 1536 + kb + scol,                       \
             lBb + (buf) * 8192 + 4096 + wid * 1024);                           \
  } while (0)

  STAGE(0, 0);
  __syncthreads();

  for (int kt = 0; kt < 24; ++kt) {
    const int cur = kt & 1;
    if (kt + 1 < 24) STAGE(cur ^ 1, kt + 1);
    bf16v8 af[4], bfv[4];
#pragma unroll
    for (int i = 0; i < 4; ++i) {
      af[i]  = *(const bf16v8*)&lA[cur][(wr * 64 + i * 16 + l16) * 32 + g * 8];
      bfv[i] = *(const bf16v8*)&lB[cur][(wc * 64 + i * 16 + l16) * 32 + g * 8];
    }
#pragma unroll
    for (int i = 0; i < 4; ++i)
#pragma unroll
      for (int j = 0; j < 4; ++j)
        acc[i][j] = mfma16(af[i], bfv[j], acc[i][j]);
    __syncthreads();
  }
#undef STAGE

  const int row0 = m0 + wr * 64, col0 = n0 + wc * 64;
#pragma unroll
  for (int j = 0; j < 4; ++j) {
    const int col = col0 + j * 16 + l16;
    const float bcol = BIASROW ? 0.f : bias[col];
#pragma unroll
    for (int i = 0; i < 4; ++i) {
#pragma unroll
      for (int r = 0; r < 4; ++r) {
        const int row = row0 + i * 16 + g * 4 + r;
        const float bv = BIASROW ? bias[row] : bcol;
        const float v = (acc[i][j][r] + bv) * scale;
        if (OUTF32) ((float*)Cv)[(size_t)row * N + col] = v;
        else        ((u16*)Cv)[(size_t)row * N + col] = f2b(v);
      }
    }
  }
}

// ----------------------------------------------------------- flash attn ----
// QK: [B*S][1536] bf16 (Q at cols n*64.., K at 768+n*64..); Q pre-scaled by
// log2e/8 (exp2 domain).  Vt: [768][8192] bf16 (row n*64+h, col b*1024+s).
// Z: [B*S][768] bf16.
// Grid: 384 blocks = 96 heads x 4 q-block pairs; id%8 keyed to head%8 so each
// head's blocks stay on one XCD (12 heads x 256KB = 3MB < 4MB L2).
// Each block processes 128-row q-block (7-p) for 16-2p chunks, THEN q-block p
// for 2p+2 chunks (restaged): exactly 18 chunks for EVERY block -> flat
// makespan, no tail.  K/V chunks (64 kv) double-buffered in LDS via
// global_load_lds (linear dest, XOR-pre-swizzled source; reads use the same
// involution -> conflict-free b128).  Swapped QK^T: softmax lane-local.
__global__ __launch_bounds__(256) void flash5_kernel(
    const u16* __restrict__ QK, const u16* __restrict__ Vt,
    u16* __restrict__ Z) {
  __shared__ u16 lK[2][64 * 64];
  __shared__ u16 lV[2][64 * 64];
  __shared__ u16 lP[4][32 * 72];

  const int tid = threadIdx.x;
  const int lane = tid & 63, wid = tid >> 6;
  const int g = lane >> 4, l16 = lane & 15;

  const int id = blockIdx.x;
  const int xs = id & 7;
  const int rest = id >> 3;                  // 0..47
  const int p = rest & 3;                    // pair selector
  const int head = xs + ((rest >> 2) << 3);  // head%8 == xs
  const int b = head / 12, n = head % 12;

  const int steps_hi = 16 - 2 * p;           // chunks for q-block 7-p
  const int total = 18;

  const u16* Qh = QK + (size_t)b * 1024 * 1536 + n * 64;
  const u16* Kh = Qh + 768;
  const u16* Vh = Vt + (size_t)n * 64 * 8192 + b * 1024;
  u16* Zh = Z + (size_t)b * 1024 * 768 + n * 64;
  u16* myP = &lP[wid][0];

  // staging: lane -> (row-in-8, 16B slot), source pre-swizzled (involution)
  const int srow8 = lane >> 3;
  const int sslot = lane & 7;
  const int scol = ((sslot ^ srow8) << 4);

#define FSTAGE(buf, c)                                                        \
  do {                                                                        \
    const int kv0_ = (c) << 6;                                                \
    const char* kb_ = (const char*)Kh + (size_t)(kv0_ + (wid << 4)) * 3072;   \
    const char* vb_ = (const char*)Vh + (size_t)(wid << 4) * 16384 +          \
                      (size_t)kv0_ * 2;                                       \
    gl_lds16(kb_ + (size_t)srow8 * 3072 + scol,                               \
             (char*)&lK[buf][0] + (wid << 11));                               \
    gl_lds16(kb_ + (size_t)(8 + srow8) * 3072 + scol,                         \
             (char*)&lK[buf][0] + (wid << 11) + 1024);                        \
    gl_lds16(vb_ + (size_t)srow8 * 16384 + scol,                              \
             (char*)&lV[buf][0] + (wid << 11));                               \
    gl_lds16(vb_ + (size_t)(8 + srow8) * 16384 + scol,                        \
             (char*)&lV[buf][0] + (wid << 11) + 1024);                        \
  } while (0)

  // swizzled LDS read index (u16): row*64 + ((slot ^ (row&7)) * 8)
#define SWZ(row, slot) (((row) << 6) + ((((slot) ^ ((row) & 7))) << 3))

  // preload Q fragments for both tiles: qf[phase][qt][kk]
  bf16v8 qf[2][2][2];
#pragma unroll
  for (int ph = 0; ph < 2; ++ph) {
    const int qw_ = (ph ? p : 7 - p) * 128 + (wid << 5);
#pragma unroll
    for (int qt = 0; qt < 2; ++qt)
#pragma unroll
      for (int kk = 0; kk < 2; ++kk)
        qf[ph][qt][kk] = *(const bf16v8*)(
            Qh + (size_t)(qw_ + qt * 16 + l16) * 1536 + kk * 32 + g * 8);
  }

  f32x4 po[2][4];
#pragma unroll
  for (int qt = 0; qt < 2; ++qt)
#pragma unroll
    for (int ht = 0; ht < 4; ++ht) po[qt][ht] = (f32x4)0.f;
  float m[2] = {-3e38f, -3e38f};
  float l[2] = {0.f, 0.f};

  FSTAGE(0, 0);
  __syncthreads();

  for (int s = 0; s < total; ++s) {
    const int cur = s & 1;
    const int ph = (s >= steps_hi) ? 1 : 0;
    const int c = ph ? s - steps_hi : s;
    const int kv0 = c << 6;
    const int qw = (ph ? p : 7 - p) * 128 + (wid << 5);

    if (s + 1 < total) {
      const int s1 = s + 1;
      const int c1 = (s1 >= steps_hi) ? s1 - steps_hi : s1;
      FSTAGE(cur ^ 1, c1);
    }

    if (kv0 <= qw + 31) {  // wave has unmasked rows in this chunk
      // K fragments (A-operand) from LDS
      bf16v8 kf[4][2];
#pragma unroll
      for (int kvt = 0; kvt < 4; ++kvt)
#pragma unroll
        for (int kk = 0; kk < 2; ++kk)
          kf[kvt][kk] =
              *(const bf16v8*)&lK[cur][SWZ(kvt * 16 + l16, kk * 4 + g)];
      // S^T[kv][q] (log2 domain)
      f32x4 s_[4][2];
#pragma unroll
      for (int kvt = 0; kvt < 4; ++kvt)
#pragma unroll
        for (int qt = 0; qt < 2; ++qt) {
          f32x4 a = (f32x4)0.f;
          a = mfma16(kf[kvt][0], qf[ph][qt][0], a);
          a = mfma16(kf[kvt][1], qf[ph][qt][1], a);
          s_[kvt][qt] = a;
        }
      // V^T fragments (B-operand) from LDS
      bf16v8 vf[4][2];
#pragma unroll
      for (int ht = 0; ht < 4; ++ht)
#pragma unroll
        for (int kk = 0; kk < 2; ++kk)
          vf[ht][kk] =
              *(const bf16v8*)&lV[cur][SWZ(ht * 16 + l16, kk * 4 + g)];
      if (kv0 + 63 > qw) {  // boundary: causal mask kv > q
#pragma unroll
        for (int kvt = 0; kvt < 4; ++kvt) {
          const int kv = kv0 + kvt * 16 + g * 4;
#pragma unroll
          for (int qt = 0; qt < 2; ++qt) {
            const int qq = qw + qt * 16 + l16;
#pragma unroll
            for (int r = 0; r < 4; ++r)
              if (kv + r > qq) s_[kvt][qt][r] = -3e38f;
          }
        }
      }
      // online softmax: q-row = l16 lane-local over kv
#pragma unroll
      for (int qt = 0; qt < 2; ++qt) {
        float cm = s_[0][qt][0];
#pragma unroll
        for (int kvt = 0; kvt < 4; ++kvt)
#pragma unroll
          for (int r = 0; r < 4; ++r) cm = fmaxf(cm, s_[kvt][qt][r]);
        cm = fmaxf(cm, __shfl_xor(cm, 16));
        cm = fmaxf(cm, __shfl_xor(cm, 32));
        const float mn = fmaxf(m[qt], cm);
        const float scl = exp2f(m[qt] - mn);
        m[qt] = mn;
        float rs = 0.f;
#pragma unroll
        for (int kvt = 0; kvt < 4; ++kvt) {
          u16x4 pw;
#pragma unroll
          for (int r = 0; r < 4; ++r) {
            const float pv = exp2f(s_[kvt][qt][r] - mn);
            rs += pv;
            pw[r] = f2b(pv);
          }
          *(u16x4*)&myP[(qt * 16 + l16) * 72 + kvt * 16 + g * 4] = pw;
        }
        rs += __shfl_xor(rs, 16);
        rs += __shfl_xor(rs, 32);
        l[qt] = l[qt] * scl + rs;
#pragma unroll
        for (int r = 0; r < 4; ++r) {
          const float sr = __shfl(scl, g * 4 + r);
#pragma unroll
          for (int ht = 0; ht < 4; ++ht) po[qt][ht][r] *= sr;
        }
      }
      // P fragments (A-operand) from wave-private LDS
      bf16v8 pa[2][2];
#pragma unroll
      for (int mt = 0; mt < 2; ++mt)
#pragma unroll
        for (int kk = 0; kk < 2; ++kk)
          pa[mt][kk] = *(const bf16v8*)&myP[(mt * 16 + l16) * 72 +
                                            kk * 32 + g * 8];
#pragma unroll
      for (int ht = 0; ht < 4; ++ht)
#pragma unroll
        for (int mt = 0; mt < 2; ++mt) {
          po[mt][ht] = mfma16(pa[mt][0], vf[ht][0], po[mt][ht]);
          po[mt][ht] = mfma16(pa[mt][1], vf[ht][1], po[mt][ht]);
        }
    }
    __syncthreads();

    // phase end: write out this tile, reset state for the next phase
    if (s == steps_hi - 1 || s == total - 1) {
#pragma unroll
      for (int qt = 0; qt < 2; ++qt) {
#pragma unroll
        for (int r = 0; r < 4; ++r) {
          const float lr = __shfl(l[qt], g * 4 + r);
          const float inv = 1.f / lr;
          const int qq = qw + qt * 16 + g * 4 + r;
#pragma unroll
          for (int ht = 0; ht < 4; ++ht)
            Zh[(size_t)qq * 768 + ht * 16 + l16] = f2b(po[qt][ht][r] * inv);
        }
      }
#pragma unroll
      for (int qt = 0; qt < 2; ++qt) {
        m[qt] = -3e38f;
        l[qt] = 0.f;
#pragma unroll
        for (int ht = 0; ht < 4; ++ht) po[qt][ht] = (f32x4)0.f;
      }
    }
  }
#undef FSTAGE
#undef SWZ
}

// ---------------------------------------------------------------- launch ----
extern "C" void kernel_launch(void* const* d_in, const int* in_sizes, int n_in,
                              void* d_out, int out_size, void* d_ws,
                              size_t ws_size, hipStream_t stream) {
  const float* x  = (const float*)d_in[0];
  const float* wq = (const float*)d_in[1];
  const float* wk = (const float*)d_in[2];
  const float* wv = (const float*)d_in[3];
  const float* wo = (const float*)d_in[4];
  const float* bq = (const float*)d_in[5];
  const float* bk = (const float*)d_in[6];
  const float* bv = (const float*)d_in[7];
  const float* bo = (const float*)d_in[8];
  float* out = (float*)d_out;

  const float sq = 0.18033688011112042f;  // log2(e) / sqrt(64)

  char* ws = (char*)d_ws;
  u16* Xb   = (u16*)ws; ws += 12582912;   // [8192][768] bf16
  u16* BtQK = (u16*)ws; ws += 2359296;    // [1536][768] bf16: WqT*sq | WkT
  u16* WvT  = (u16*)ws; ws += 1179648;    // [768][768]
  u16* WoT  = (u16*)ws; ws += 1179648;    // [768][768]
  float* bc = (float*)ws; ws += 6144;     // [1536] fp32: bq*sq | bk
  u16* QKb  = (u16*)ws; ws += 25165824;   // [8192][1536] (Q | K)
  u16* Vtb  = (u16*)ws; ws += 12582912;   // [768][8192]  (V transposed)
  u16* Zb   = (u16*)ws; ws += 12582912;   // [8192][768]

  pack_x_kernel<<<3072, 256, 0, stream>>>(x, Xb, 786432);
  pack_w_kernel<<<dim3(12, 1, 12), 256, 0, stream>>>(wq, BtQK, 49152, 64,
                                                     49152, 768, sq);
  pack_w_kernel<<<dim3(12, 1, 12), 256, 0, stream>>>(wk, BtQK + 589824, 49152,
                                                     64, 49152, 768, 1.0f);
  pack_w_kernel<<<dim3(12, 1, 12), 256, 0, stream>>>(wv, WvT, 49152, 64,
                                                     49152, 768, 1.0f);
  pack_w_kernel<<<dim3(1, 12, 12), 256, 0, stream>>>(wo, WoT, 49152, 768,
                                                     64, 768, 1.0f);
  pack_bias_kernel<<<6, 256, 0, stream>>>(bq, bk, bc, sq);

  // fused Q|K projection: [8192][1536]
  gemm_bt<0, 0><<<dim3(64, 12), 256, 0, stream>>>(Xb, BtQK, QKb, bc, 1.0f,
                                                  1536);
  // V^T = (Wv^T) . X^T directly: A = WvT [768][768], Bt = Xb [8192][768]
  gemm_bt<0, 1><<<dim3(6, 64), 256, 0, stream>>>(WvT, Xb, Vtb, bv, 1.0f, 8192);

  flash5_kernel<<<dim3(384), 256, 0, stream>>>(QKb, Vtb, Zb);

  gemm_bt<1, 0><<<dim3(64, 6), 256, 0, stream>>>(Zb, WoT, out, bo, 1.0f, 768);
}

// Round 8
// 131.445 us; speedup vs baseline: 1.2765x; 1.1294x over previous
//
#include <hip/hip_runtime.h>
#include <stdint.h>

typedef __attribute__((ext_vector_type(4))) float f32x4;
typedef __attribute__((ext_vector_type(8))) __bf16 bf16v8;
typedef __attribute__((ext_vector_type(8))) unsigned short u16x8;
typedef __attribute__((ext_vector_type(4))) unsigned short u16x4;
typedef unsigned short u16;

#define AS1 __attribute__((address_space(1)))
#define AS3 __attribute__((address_space(3)))

__device__ __forceinline__ u16 f2b(float f) {
  union { __bf16 h; u16 u; } c; c.h = (__bf16)f; return c.u;
}

__device__ __forceinline__ f32x4 mfma16(bf16v8 a, bf16v8 b, f32x4 c) {
  return __builtin_amdgcn_mfma_f32_16x16x32_bf16(a, b, c, 0, 0, 0);
}

__device__ __forceinline__ void gl_lds16(const void* g, void* l) {
  __builtin_amdgcn_global_load_lds((AS1 void*)g, (AS3 void*)l, 16, 0, 0);
}

// ---------------------------------------------------------------- pack x ----
__global__ __launch_bounds__(256) void pack_x_kernel(
    const float* __restrict__ x, u16* __restrict__ xb, int n8) {
  int i = blockIdx.x * 256 + threadIdx.x;
  if (i >= n8) return;
  const f32x4* p = (const f32x4*)(x + (size_t)i * 8);
  f32x4 a = p[0], b = p[1];
  u16x8 o;
  o[0] = f2b(a[0]); o[1] = f2b(a[1]); o[2] = f2b(a[2]); o[3] = f2b(a[3]);
  o[4] = f2b(b[0]); o[5] = f2b(b[1]); o[6] = f2b(b[2]); o[7] = f2b(b[3]);
  *(u16x8*)(xb + (size_t)i * 8) = o;
}

// --------------------------------------------------------- pack weights ----
// out[n*out_ns + b*out_rs + a] = bf16(scale * in[n*in_ns + a*in_rs + b])
__global__ __launch_bounds__(256) void pack_w_kernel(
    const float* __restrict__ in, u16* __restrict__ out,
    int in_ns, int in_rs, int out_ns, int out_rs, float scale) {
  __shared__ float t[64][65];
  const int n = blockIdx.z;
  const int a0 = blockIdx.x * 64, b0 = blockIdx.y * 64;
  const int c = threadIdx.x & 63, w = threadIdx.x >> 6;
  const float* ip = in + (size_t)n * in_ns;
#pragma unroll
  for (int i = 0; i < 16; ++i) {
    int r = i * 4 + w;
    t[r][c] = ip[(size_t)(a0 + r) * in_rs + (b0 + c)];
  }
  __syncthreads();
  u16* op = out + (size_t)n * out_ns;
#pragma unroll
  for (int i = 0; i < 16; ++i) {
    int r = i * 4 + w;
    op[(size_t)(b0 + r) * out_rs + (a0 + c)] = f2b(t[c][r] * scale);
  }
}

// ------------------------------------------------------------- pack bias ----
__global__ __launch_bounds__(256) void pack_bias_kernel(
    const float* __restrict__ bq, const float* __restrict__ bk,
    float* __restrict__ o, float sq) {
  int i = blockIdx.x * 256 + threadIdx.x;
  if (i < 768) o[i] = bq[i] * sq;
  else if (i < 1536) o[i] = bk[i - 768];
}

// ------------------------------------------------------------------ GEMM ----
// C[m][col] = (sum_k A[m][k]*Bt[col][k] + bias[BIASROW? m : col]) * scale
template <int OUTF32, int BIASROW>
__global__ __launch_bounds__(256, 2) void gemm_bt(
    const u16* __restrict__ A, const u16* __restrict__ Bt,
    void* __restrict__ Cv, const float* __restrict__ bias, float scale, int N) {
  constexpr int K = 768;
  __shared__ u16 lA[2][128 * 32];
  __shared__ u16 lB[2][128 * 32];

  const int tid = threadIdx.x;
  const int lane = tid & 63, wid = tid >> 6;
  const int wr = wid >> 1, wc = wid & 1;
  const int g = lane >> 4, l16 = lane & 15;
  const int m0 = blockIdx.x * 128, n0 = blockIdx.y * 128;

  const int srow = tid >> 2;
  const int scol = (tid & 3) * 16;

  f32x4 acc[4][4];
#pragma unroll
  for (int i = 0; i < 4; ++i)
#pragma unroll
    for (int j = 0; j < 4; ++j) acc[i][j] = (f32x4)0.f;

  const char* Ab = (const char*)(A + (size_t)m0 * K);
  const char* Bb = (const char*)(Bt + (size_t)n0 * K);
  char* lAb = (char*)&lA[0][0];
  char* lBb = (char*)&lB[0][0];

#define STAGE(buf, kt)                                                          \
  do {                                                                          \
    int kb = (kt) * 64;                                                         \
    gl_lds16(Ab + (size_t)srow * 1536 + kb + scol,                              \
             lAb + (buf) * 8192 + wid * 1024);                                  \
    gl_lds16(Bb + (size_t)srow * 1536 + kb + scol,                              \
             lBb + (buf) * 8192 + wid * 1024);                                  \
    gl_lds16(Ab + (size_t)(64 + srow) * 1536 + kb + scol,                       \
             lAb + (buf) * 8192 + 4096 + wid * 1024);                           \
    gl_lds16(Bb + (size_t)(64 + srow) * 1536 + kb + scol,                       \
             lBb + (buf) * 8192 + 4096 + wid * 1024);                           \
  } while (0)

  STAGE(0, 0);
  __syncthreads();

  for (int kt = 0; kt < 24; ++kt) {
    const int cur = kt & 1;
    if (kt + 1 < 24) STAGE(cur ^ 1, kt + 1);
    bf16v8 af[4], bfv[4];
#pragma unroll
    for (int i = 0; i < 4; ++i) {
      af[i]  = *(const bf16v8*)&lA[cur][(wr * 64 + i * 16 + l16) * 32 + g * 8];
      bfv[i] = *(const bf16v8*)&lB[cur][(wc * 64 + i * 16 + l16) * 32 + g * 8];
    }
#pragma unroll
    for (int i = 0; i < 4; ++i)
#pragma unroll
      for (int j = 0; j < 4; ++j)
        acc[i][j] = mfma16(af[i], bfv[j], acc[i][j]);
    __syncthreads();
  }
#undef STAGE

  const int row0 = m0 + wr * 64, col0 = n0 + wc * 64;
#pragma unroll
  for (int j = 0; j < 4; ++j) {
    const int col = col0 + j * 16 + l16;
    const float bcol = BIASROW ? 0.f : bias[col];
#pragma unroll
    for (int i = 0; i < 4; ++i) {
#pragma unroll
      for (int r = 0; r < 4; ++r) {
        const int row = row0 + i * 16 + g * 4 + r;
        const float bv = BIASROW ? bias[row] : bcol;
        const float v = (acc[i][j][r] + bv) * scale;
        if (OUTF32) ((float*)Cv)[(size_t)row * N + col] = v;
        else        ((u16*)Cv)[(size_t)row * N + col] = f2b(v);
      }
    }
  }
}

// ----------------------------------------------------------- flash attn ----
// QK: [B*S][1536] bf16 (Q at cols n*64.., K at 768+n*64..); Q pre-scaled by
// log2e/8 (exp2 domain).  Vt: [768][8192] bf16 (row n*64+h, col b*1024+s).
// Z: [B*S][768] bf16.
// Grid: 768 blocks = 96 heads x 8 half-block pairs -> EXACTLY 3 blocks/CU.
// Half-block hq = 64 q-rows needs hq+1 chunks; block p does half-block (15-p)
// then half-block p: (16-p)+(p+1) = 17 chunks for EVERY block (flat makespan
// at both block and CU granularity).  4 waves x 16 q-rows per phase.
// K/V chunks (64 kv) double-buffered in LDS via global_load_lds (linear dest,
// XOR-pre-swizzled source; reads use same involution -> conflict-free b128).
// id%8 == head%8 keeps each head's blocks on one XCD (12 heads x 256KB = 3MB
// < 4MB L2).  Swapped QK^T: softmax lane-local; shared lP (wave-private
// slices, no cross-wave sync needed).
// NOTE: causal-mask trigger must be (kv0 + 63 > qw): mask needed when the
// chunk's max kv exceeds the wave's MIN q-row (R7 bug: +48 skipped wid=3).
__global__ __launch_bounds__(256, 3) void flash6_kernel(
    const u16* __restrict__ QK, const u16* __restrict__ Vt,
    u16* __restrict__ Z) {
  __shared__ u16 lK[2][64 * 64];
  __shared__ u16 lV[2][64 * 64];
  __shared__ u16 lP[64 * 72];

  const int tid = threadIdx.x;
  const int lane = tid & 63, wid = tid >> 6;
  const int g = lane >> 4, l16 = lane & 15;

  const int id = blockIdx.x;
  const int xs = id & 7;
  const int rest = id >> 3;       // 0..95
  const int p = rest & 7;         // pair selector 0..7
  const int j = rest >> 3;        // 0..11
  const int head = xs + 8 * j;    // head%8 == xs (XCD grouping)
  const int b = head / 12, n = head % 12;

  const int nchA = 16 - p;        // phase A: half-block 15-p
  const int total = 17;           // + phase B: half-block p (p+1 chunks)

  const u16* Qh = QK + (size_t)b * 1024 * 1536 + n * 64;
  const u16* Kh = Qh + 768;
  const u16* Vh = Vt + (size_t)n * 64 * 8192 + b * 1024;
  u16* Zh = Z + (size_t)b * 1024 * 768 + n * 64;
  u16* myP = &lP[(wid * 16) * 72];   // wave-private 16-row P slice

  // staging: lane -> (row-in-8, 16B slot), source pre-swizzled (involution)
  const int srow8 = lane >> 3;
  const int sslot = lane & 7;
  const int scol = ((sslot ^ srow8) << 4);

#define FSTAGE(buf, c)                                                        \
  do {                                                                        \
    const int kv0_ = (c) << 6;                                                \
    const char* kb_ = (const char*)Kh + (size_t)(kv0_ + (wid << 4)) * 3072;   \
    const char* vb_ = (const char*)Vh + (size_t)(wid << 4) * 16384 +          \
                      (size_t)kv0_ * 2;                                       \
    gl_lds16(kb_ + (size_t)srow8 * 3072 + scol,                               \
             (char*)&lK[buf][0] + (wid << 11));                               \
    gl_lds16(kb_ + (size_t)(8 + srow8) * 3072 + scol,                         \
             (char*)&lK[buf][0] + (wid << 11) + 1024);                        \
    gl_lds16(vb_ + (size_t)srow8 * 16384 + scol,                              \
             (char*)&lV[buf][0] + (wid << 11));                               \
    gl_lds16(vb_ + (size_t)(8 + srow8) * 16384 + scol,                        \
             (char*)&lV[buf][0] + (wid << 11) + 1024);                        \
  } while (0)

  // swizzled LDS read index (u16): row*64 + ((slot ^ (row&7)) * 8)
#define SWZ(row, slot) (((row) << 6) + ((((slot) ^ ((row) & 7))) << 3))

  // Q fragments for both phases (16 rows each)
  const int qwA = (15 - p) * 64 + wid * 16;
  const int qwB = p * 64 + wid * 16;
  bf16v8 qfA[2], qfB[2];
#pragma unroll
  for (int kk = 0; kk < 2; ++kk) {
    qfA[kk] = *(const bf16v8*)(Qh + (size_t)(qwA + l16) * 1536 + kk * 32 + g * 8);
    qfB[kk] = *(const bf16v8*)(Qh + (size_t)(qwB + l16) * 1536 + kk * 32 + g * 8);
  }

  f32x4 po[4];
#pragma unroll
  for (int ht = 0; ht < 4; ++ht) po[ht] = (f32x4)0.f;
  float m = -3e38f, l = 0.f;

  FSTAGE(0, 0);
  __syncthreads();

  for (int s = 0; s < total; ++s) {
    const int cur = s & 1;
    const bool phB = s >= nchA;
    const int c = phB ? s - nchA : s;
    const int kv0 = c << 6;
    const int qw = phB ? qwB : qwA;

    if (s + 1 < total) {
      const int s1 = s + 1;
      const int c1 = (s1 >= nchA) ? s1 - nchA : s1;
      FSTAGE(cur ^ 1, c1);
    }

    const bf16v8 q0 = phB ? qfB[0] : qfA[0];
    const bf16v8 q1 = phB ? qfB[1] : qfA[1];

    // K fragments (A-operand) from LDS
    bf16v8 kf[4][2];
#pragma unroll
    for (int kvt = 0; kvt < 4; ++kvt)
#pragma unroll
      for (int kk = 0; kk < 2; ++kk)
        kf[kvt][kk] =
            *(const bf16v8*)&lK[cur][SWZ(kvt * 16 + l16, kk * 4 + g)];
    // S^T[kv][q] (log2 domain): col=l16 -> q, row=g*4+r -> kv
    f32x4 s_[4];
#pragma unroll
    for (int kvt = 0; kvt < 4; ++kvt) {
      f32x4 a = (f32x4)0.f;
      a = mfma16(kf[kvt][0], q0, a);
      a = mfma16(kf[kvt][1], q1, a);
      s_[kvt] = a;
    }
    // V^T fragments (B-operand) from LDS
    bf16v8 vf[4][2];
#pragma unroll
    for (int ht = 0; ht < 4; ++ht)
#pragma unroll
      for (int kk = 0; kk < 2; ++kk)
        vf[ht][kk] =
            *(const bf16v8*)&lV[cur][SWZ(ht * 16 + l16, kk * 4 + g)];

    if (kv0 + 63 > qw) {  // causal mask: chunk's max kv exceeds wave's min q
      const int qq = qw + l16;
#pragma unroll
      for (int kvt = 0; kvt < 4; ++kvt) {
        const int kv = kv0 + kvt * 16 + g * 4;
#pragma unroll
        for (int r = 0; r < 4; ++r)
          if (kv + r > qq) s_[kvt][r] = -3e38f;
      }
    }
    // online softmax: q-row = l16 lane-local over kv
    {
      float cm = s_[0][0];
#pragma unroll
      for (int kvt = 0; kvt < 4; ++kvt)
#pragma unroll
        for (int r = 0; r < 4; ++r) cm = fmaxf(cm, s_[kvt][r]);
      cm = fmaxf(cm, __shfl_xor(cm, 16));
      cm = fmaxf(cm, __shfl_xor(cm, 32));
      const float mn = fmaxf(m, cm);
      const float scl = exp2f(m - mn);
      m = mn;
      float rs = 0.f;
#pragma unroll
      for (int kvt = 0; kvt < 4; ++kvt) {
        u16x4 pw;
#pragma unroll
        for (int r = 0; r < 4; ++r) {
          const float pv = exp2f(s_[kvt][r] - mn);
          rs += pv;
          pw[r] = f2b(pv);
        }
        *(u16x4*)&myP[l16 * 72 + kvt * 16 + g * 4] = pw;
      }
      rs += __shfl_xor(rs, 16);
      rs += __shfl_xor(rs, 32);
      l = l * scl + rs;
#pragma unroll
      for (int r = 0; r < 4; ++r) {
        const float sr = __shfl(scl, g * 4 + r);
#pragma unroll
        for (int ht = 0; ht < 4; ++ht) po[ht][r] *= sr;
      }
    }
    // P fragments (A-operand) from wave-private LDS slice
    bf16v8 pa[2];
#pragma unroll
    for (int kk = 0; kk < 2; ++kk)
      pa[kk] = *(const bf16v8*)&myP[l16 * 72 + kk * 32 + g * 8];
#pragma unroll
    for (int ht = 0; ht < 4; ++ht) {
      po[ht] = mfma16(pa[0], vf[ht][0], po[ht]);
      po[ht] = mfma16(pa[1], vf[ht][1], po[ht]);
    }

    __syncthreads();

    // phase end: write out this half-block's 16 rows, reset state
    if (s == nchA - 1 || s == total - 1) {
#pragma unroll
      for (int r = 0; r < 4; ++r) {
        const float lr = __shfl(l, g * 4 + r);
        const float inv = 1.f / lr;
        const int qq = qw + g * 4 + r;
#pragma unroll
        for (int ht = 0; ht < 4; ++ht)
          Zh[(size_t)qq * 768 + ht * 16 + l16] = f2b(po[ht][r] * inv);
      }
      m = -3e38f;
      l = 0.f;
#pragma unroll
      for (int ht = 0; ht < 4; ++ht) po[ht] = (f32x4)0.f;
    }
  }
#undef FSTAGE
#undef SWZ
}

// ---------------------------------------------------------------- launch ----
extern "C" void kernel_launch(void* const* d_in, const int* in_sizes, int n_in,
                              void* d_out, int out_size, void* d_ws,
                              size_t ws_size, hipStream_t stream) {
  const float* x  = (const float*)d_in[0];
  const float* wq = (const float*)d_in[1];
  const float* wk = (const float*)d_in[2];
  const float* wv = (const float*)d_in[3];
  const float* wo = (const float*)d_in[4];
  const float* bq = (const float*)d_in[5];
  const float* bk = (const float*)d_in[6];
  const float* bv = (const float*)d_in[7];
  const float* bo = (const float*)d_in[8];
  float* out = (float*)d_out;

  const float sq = 0.18033688011112042f;  // log2(e) / sqrt(64)

  char* ws = (char*)d_ws;
  u16* Xb   = (u16*)ws; ws += 12582912;   // [8192][768] bf16
  u16* BtQK = (u16*)ws; ws += 2359296;    // [1536][768] bf16: WqT*sq | WkT
  u16* WvT  = (u16*)ws; ws += 1179648;    // [768][768]
  u16* WoT  = (u16*)ws; ws += 1179648;    // [768][768]
  float* bc = (float*)ws; ws += 6144;     // [1536] fp32: bq*sq | bk
  u16* QKb  = (u16*)ws; ws += 25165824;   // [8192][1536] (Q | K)
  u16* Vtb  = (u16*)ws; ws += 12582912;   // [768][8192]  (V transposed)
  u16* Zb   = (u16*)ws; ws += 12582912;   // [8192][768]

  pack_x_kernel<<<3072, 256, 0, stream>>>(x, Xb, 786432);
  pack_w_kernel<<<dim3(12, 1, 12), 256, 0, stream>>>(wq, BtQK, 49152, 64,
                                                     49152, 768, sq);
  pack_w_kernel<<<dim3(12, 1, 12), 256, 0, stream>>>(wk, BtQK + 589824, 49152,
                                                     64, 49152, 768, 1.0f);
  pack_w_kernel<<<dim3(12, 1, 12), 256, 0, stream>>>(wv, WvT, 49152, 64,
                                                     49152, 768, 1.0f);
  pack_w_kernel<<<dim3(1, 12, 12), 256, 0, stream>>>(wo, WoT, 49152, 768,
                                                     64, 768, 1.0f);
  pack_bias_kernel<<<6, 256, 0, stream>>>(bq, bk, bc, sq);

  // fused Q|K projection: [8192][1536]
  gemm_bt<0, 0><<<dim3(64, 12), 256, 0, stream>>>(Xb, BtQK, QKb, bc, 1.0f,
                                                  1536);
  // V^T = (Wv^T) . X^T directly: A = WvT [768][768], Bt = Xb [8192][768]
  gemm_bt<0, 1><<<dim3(6, 64), 256, 0, stream>>>(WvT, Xb, Vtb, bv, 1.0f, 8192);

  flash6_kernel<<<dim3(768), 256, 0, stream>>>(QKb, Vtb, Zb);

  gemm_bt<1, 0><<<dim3(64, 6), 256, 0, stream>>>(Zb, WoT, out, bo, 1.0f, 768);
}

// Round 9
// 119.661 us; speedup vs baseline: 1.4022x; 1.0985x over previous
//
#include <hip/hip_runtime.h>
#include <stdint.h>

typedef __attribute__((ext_vector_type(4))) float f32x4;
typedef __attribute__((ext_vector_type(8))) __bf16 bf16v8;
typedef __attribute__((ext_vector_type(8))) unsigned short u16x8;
typedef __attribute__((ext_vector_type(4))) unsigned short u16x4;
typedef unsigned short u16;

#define AS1 __attribute__((address_space(1)))
#define AS3 __attribute__((address_space(3)))

__device__ __forceinline__ u16 f2b(float f) {
  union { __bf16 h; u16 u; } c; c.h = (__bf16)f; return c.u;
}

__device__ __forceinline__ f32x4 mfma16(bf16v8 a, bf16v8 b, f32x4 c) {
  return __builtin_amdgcn_mfma_f32_16x16x32_bf16(a, b, c, 0, 0, 0);
}

__device__ __forceinline__ void gl_lds16(const void* g, void* l) {
  __builtin_amdgcn_global_load_lds((AS1 void*)g, (AS3 void*)l, 16, 0, 0);
}

// ------------------------------------------------- pack x (+ bias tail) ----
__global__ __launch_bounds__(256) void pack_x_kernel(
    const float* __restrict__ x, u16* __restrict__ xb, int n8,
    const float* __restrict__ bq, const float* __restrict__ bk,
    float* __restrict__ bc, float sq) {
  int i = blockIdx.x * 256 + threadIdx.x;
  if (i < n8) {
    const f32x4* p = (const f32x4*)(x + (size_t)i * 8);
    f32x4 a = p[0], b = p[1];
    u16x8 o;
    o[0] = f2b(a[0]); o[1] = f2b(a[1]); o[2] = f2b(a[2]); o[3] = f2b(a[3]);
    o[4] = f2b(b[0]); o[5] = f2b(b[1]); o[6] = f2b(b[2]); o[7] = f2b(b[3]);
    *(u16x8*)(xb + (size_t)i * 8) = o;
  } else {
    int j = i - n8;
    if (j < 768) bc[j] = bq[j] * sq;
    else if (j < 1536) bc[j] = bk[j - 768];
  }
}

// --------------------------------------------------- pack all weights ------
// grid (12, 1, 48): z = which*12 + n.  64x64 transpose tiles.
// which 0: wq*sq -> BtQK      (in_rs 64)
// which 1: wk    -> BtQK+589824
// which 2: wv    -> WvT
// which 3: wo    -> WoT (out_ns 64, in_rs 768, b-tiles on blockIdx.x)
__global__ __launch_bounds__(256) void pack_w_all(
    const float* __restrict__ wq, const float* __restrict__ wk,
    const float* __restrict__ wv, const float* __restrict__ wo,
    u16* __restrict__ btqk, u16* __restrict__ wvt, u16* __restrict__ wot,
    float sq) {
  __shared__ float t[64][65];
  const int z = blockIdx.z;
  const int which = z / 12, n = z % 12;
  const int c = threadIdx.x & 63, w = threadIdx.x >> 6;

  const float* in; u16* out; int in_rs, out_ns; float scale;
  int a0, b0;
  if (which == 0) { in = wq; out = btqk;          in_rs = 64;  out_ns = 49152; scale = sq;  }
  else if (which == 1) { in = wk; out = btqk + 589824; in_rs = 64; out_ns = 49152; scale = 1.f; }
  else if (which == 2) { in = wv; out = wvt;      in_rs = 64;  out_ns = 49152; scale = 1.f; }
  else { in = wo; out = wot;                      in_rs = 768; out_ns = 64;    scale = 1.f; }
  if (which < 3) { a0 = blockIdx.x * 64; b0 = 0; }
  else           { a0 = 0; b0 = blockIdx.x * 64; }

  const float* ip = in + (size_t)n * 49152;
#pragma unroll
  for (int i = 0; i < 16; ++i) {
    int r = i * 4 + w;
    t[r][c] = ip[(size_t)(a0 + r) * in_rs + (b0 + c)];
  }
  __syncthreads();
  u16* op = out + (size_t)n * out_ns;
#pragma unroll
  for (int i = 0; i < 16; ++i) {
    int r = i * 4 + w;
    op[(size_t)(b0 + r) * 768 + (a0 + c)] = f2b(t[c][r] * scale);
  }
}

// ------------------------------------------------------------------ GEMM ----
// C[m][col] = (sum_k A[m][k]*Bt[col][k] + bias[BIASROW? m : col]) * scale
// A: [M][768] bf16, Bt: [Ncols][768] bf16.
// TN=128: 128x128 tile, 2x2 waves x (64x64), acc[4][4].
// TN=64 : 128x64 tile, 4x1 waves x (32x64), acc[2][4].
// Always launch grids totaling 768 blocks -> exactly 3 blocks/CU (flat).
template <int OUTF32, int BIASROW, int TN>
__global__ __launch_bounds__(256, 3) void gemm_bt(
    const u16* __restrict__ A, const u16* __restrict__ Bt,
    void* __restrict__ Cv, const float* __restrict__ bias, float scale, int N) {
  constexpr int K = 768;
  constexpr int MI = (TN == 128) ? 4 : 2;
  __shared__ u16 lA[2][128 * 32];
  __shared__ u16 lB[2][TN * 32];
  constexpr int BBUF = TN * 64;  // bytes per B buffer

  const int tid = threadIdx.x;
  const int lane = tid & 63, wid = tid >> 6;
  const int g = lane >> 4, l16 = lane & 15;
  const int rowb = (TN == 128) ? (wid >> 1) * 64 : wid * 32;
  const int colb = (TN == 128) ? (wid & 1) * 64 : 0;
  const int m0 = blockIdx.x * 128, n0 = blockIdx.y * TN;

  const int srow = tid >> 2;
  const int scol = (tid & 3) * 16;

  f32x4 acc[MI][4];
#pragma unroll
  for (int i = 0; i < MI; ++i)
#pragma unroll
    for (int j = 0; j < 4; ++j) acc[i][j] = (f32x4)0.f;

  const char* Ab = (const char*)(A + (size_t)m0 * K);
  const char* Bb = (const char*)(Bt + (size_t)n0 * K);
  char* lAb = (char*)&lA[0][0];
  char* lBb = (char*)&lB[0][0];

#define STAGE(buf, kt)                                                          \
  do {                                                                          \
    int kb = (kt) * 64;                                                         \
    gl_lds16(Ab + (size_t)srow * 1536 + kb + scol,                              \
             lAb + (buf) * 8192 + wid * 1024);                                  \
    gl_lds16(Ab + (size_t)(64 + srow) * 1536 + kb + scol,                       \
             lAb + (buf) * 8192 + 4096 + wid * 1024);                           \
    if (TN == 128) {                                                            \
      gl_lds16(Bb + (size_t)srow * 1536 + kb + scol,                            \
               lBb + (buf) * BBUF + wid * 1024);                                \
      gl_lds16(Bb + (size_t)(64 + srow) * 1536 + kb + scol,                     \
               lBb + (buf) * BBUF + 4096 + wid * 1024);                         \
    } else if (srow < 64) {                                                     \
      gl_lds16(Bb + (size_t)srow * 1536 + kb + scol,                            \
               lBb + (buf) * BBUF + wid * 1024);                                \
    }                                                                           \
  } while (0)

  STAGE(0, 0);
  __syncthreads();

  for (int kt = 0; kt < 24; ++kt) {
    const int cur = kt & 1;
    if (kt + 1 < 24) STAGE(cur ^ 1, kt + 1);
    bf16v8 af[MI], bfv[4];
#pragma unroll
    for (int i = 0; i < MI; ++i)
      af[i] = *(const bf16v8*)&lA[cur][(rowb + i * 16 + l16) * 32 + g * 8];
#pragma unroll
    for (int j = 0; j < 4; ++j)
      bfv[j] = *(const bf16v8*)&lB[cur][(colb + j * 16 + l16) * 32 + g * 8];
#pragma unroll
    for (int i = 0; i < MI; ++i)
#pragma unroll
      for (int j = 0; j < 4; ++j)
        acc[i][j] = mfma16(af[i], bfv[j], acc[i][j]);
    __syncthreads();
  }
#undef STAGE

  const int row0 = m0 + rowb, col0 = n0 + colb;
#pragma unroll
  for (int j = 0; j < 4; ++j) {
    const int col = col0 + j * 16 + l16;
    const float bcol = BIASROW ? 0.f : bias[col];
#pragma unroll
    for (int i = 0; i < MI; ++i) {
#pragma unroll
      for (int r = 0; r < 4; ++r) {
        const int row = row0 + i * 16 + g * 4 + r;
        const float bv = BIASROW ? bias[row] : bcol;
        const float v = (acc[i][j][r] + bv) * scale;
        if (OUTF32) ((float*)Cv)[(size_t)row * N + col] = v;
        else        ((u16*)Cv)[(size_t)row * N + col] = f2b(v);
      }
    }
  }
}

// ----------------------------------------------------------- flash attn ----
// QK: [B*S][1536] bf16 (Q at cols n*64.., K at 768+n*64..); Q pre-scaled by
// log2e/8 (exp2 domain).  Vt: [768][8192] bf16 (row n*64+h, col b*1024+s).
// Z: [B*S][768] bf16.
// Grid: 768 blocks = 96 heads x 8 half-block pairs -> EXACTLY 3 blocks/CU.
// Block p: half-block (15-p) for 16-p chunks, then half-block p for p+1 ->
// 17 chunks for EVERY block (flat makespan).  4 waves x 16 q-rows per phase.
// K/V chunks (64 kv) double-buffered via global_load_lds (linear dest,
// XOR-pre-swizzled source; reads use same involution).  id%8 == head%8 keeps
// each head on one XCD (12 heads x 256KB = 3MB < 4MB L2).  Swapped QK^T:
// softmax lane-local.  T13 defer-rescale: skip po-rescale when max growth <=8
// (exp2 domain; P bounded by 256, fine in bf16/f32).
// Causal-mask trigger: (kv0 + 63 > qw) — max kv vs wave's MIN q (R7 bug).
__global__ __launch_bounds__(256, 3) void flash6_kernel(
    const u16* __restrict__ QK, const u16* __restrict__ Vt,
    u16* __restrict__ Z) {
  __shared__ u16 lK[2][64 * 64];
  __shared__ u16 lV[2][64 * 64];
  __shared__ u16 lP[64 * 72];

  const int tid = threadIdx.x;
  const int lane = tid & 63, wid = tid >> 6;
  const int g = lane >> 4, l16 = lane & 15;

  const int id = blockIdx.x;
  const int xs = id & 7;
  const int rest = id >> 3;       // 0..95
  const int p = rest & 7;         // pair selector 0..7
  const int j = rest >> 3;        // 0..11
  const int head = xs + 8 * j;    // head%8 == xs (XCD grouping)
  const int b = head / 12, n = head % 12;

  const int nchA = 16 - p;        // phase A: half-block 15-p
  const int total = 17;           // + phase B: half-block p (p+1 chunks)

  const u16* Qh = QK + (size_t)b * 1024 * 1536 + n * 64;
  const u16* Kh = Qh + 768;
  const u16* Vh = Vt + (size_t)n * 64 * 8192 + b * 1024;
  u16* Zh = Z + (size_t)b * 1024 * 768 + n * 64;
  u16* myP = &lP[(wid * 16) * 72];   // wave-private 16-row P slice

  const int srow8 = lane >> 3;
  const int sslot = lane & 7;
  const int scol = ((sslot ^ srow8) << 4);

#define FSTAGE(buf, c)                                                        \
  do {                                                                        \
    const int kv0_ = (c) << 6;                                                \
    const char* kb_ = (const char*)Kh + (size_t)(kv0_ + (wid << 4)) * 3072;   \
    const char* vb_ = (const char*)Vh + (size_t)(wid << 4) * 16384 +          \
                      (size_t)kv0_ * 2;                                       \
    gl_lds16(kb_ + (size_t)srow8 * 3072 + scol,                               \
             (char*)&lK[buf][0] + (wid << 11));                               \
    gl_lds16(kb_ + (size_t)(8 + srow8) * 3072 + scol,                         \
             (char*)&lK[buf][0] + (wid << 11) + 1024);                        \
    gl_lds16(vb_ + (size_t)srow8 * 16384 + scol,                              \
             (char*)&lV[buf][0] + (wid << 11));                               \
    gl_lds16(vb_ + (size_t)(8 + srow8) * 16384 + scol,                        \
             (char*)&lV[buf][0] + (wid << 11) + 1024);                        \
  } while (0)

#define SWZ(row, slot) (((row) << 6) + ((((slot) ^ ((row) & 7))) << 3))

  const int qwA = (15 - p) * 64 + wid * 16;
  const int qwB = p * 64 + wid * 16;
  bf16v8 qfA[2], qfB[2];
#pragma unroll
  for (int kk = 0; kk < 2; ++kk) {
    qfA[kk] = *(const bf16v8*)(Qh + (size_t)(qwA + l16) * 1536 + kk * 32 + g * 8);
    qfB[kk] = *(const bf16v8*)(Qh + (size_t)(qwB + l16) * 1536 + kk * 32 + g * 8);
  }

  f32x4 po[4];
#pragma unroll
  for (int ht = 0; ht < 4; ++ht) po[ht] = (f32x4)0.f;
  float m = -3e38f, l = 0.f;

  FSTAGE(0, 0);
  __syncthreads();

  for (int s = 0; s < total; ++s) {
    const int cur = s & 1;
    const bool phB = s >= nchA;
    const int c = phB ? s - nchA : s;
    const int kv0 = c << 6;
    const int qw = phB ? qwB : qwA;

    if (s + 1 < total) {
      const int s1 = s + 1;
      const int c1 = (s1 >= nchA) ? s1 - nchA : s1;
      FSTAGE(cur ^ 1, c1);
    }

    const bf16v8 q0 = phB ? qfB[0] : qfA[0];
    const bf16v8 q1 = phB ? qfB[1] : qfA[1];

    bf16v8 kf[4][2];
#pragma unroll
    for (int kvt = 0; kvt < 4; ++kvt)
#pragma unroll
      for (int kk = 0; kk < 2; ++kk)
        kf[kvt][kk] =
            *(const bf16v8*)&lK[cur][SWZ(kvt * 16 + l16, kk * 4 + g)];
    f32x4 s_[4];
#pragma unroll
    for (int kvt = 0; kvt < 4; ++kvt) {
      f32x4 a = (f32x4)0.f;
      a = mfma16(kf[kvt][0], q0, a);
      a = mfma16(kf[kvt][1], q1, a);
      s_[kvt] = a;
    }
    bf16v8 vf[4][2];
#pragma unroll
    for (int ht = 0; ht < 4; ++ht)
#pragma unroll
      for (int kk = 0; kk < 2; ++kk)
        vf[ht][kk] =
            *(const bf16v8*)&lV[cur][SWZ(ht * 16 + l16, kk * 4 + g)];

    if (kv0 + 63 > qw) {  // causal mask: chunk's max kv exceeds wave's min q
      const int qq = qw + l16;
#pragma unroll
      for (int kvt = 0; kvt < 4; ++kvt) {
        const int kv = kv0 + kvt * 16 + g * 4;
#pragma unroll
        for (int r = 0; r < 4; ++r)
          if (kv + r > qq) s_[kvt][r] = -3e38f;
      }
    }
    // online softmax (q-row = l16 lane-local over kv), T13 defer-rescale
    {
      float cm = s_[0][0];
#pragma unroll
      for (int kvt = 0; kvt < 4; ++kvt)
#pragma unroll
        for (int r = 0; r < 4; ++r) cm = fmaxf(cm, s_[kvt][r]);
      cm = fmaxf(cm, __shfl_xor(cm, 16));
      cm = fmaxf(cm, __shfl_xor(cm, 32));
      const bool defer = __all(cm - m <= 8.0f);
      float scl = 1.0f;
      if (!defer) {
        const float mn = fmaxf(m, cm);
        scl = exp2f(m - mn);
        m = mn;
#pragma unroll
        for (int r = 0; r < 4; ++r) {
          const float sr = __shfl(scl, g * 4 + r);
#pragma unroll
          for (int ht = 0; ht < 4; ++ht) po[ht][r] *= sr;
        }
      }
      float rs = 0.f;
#pragma unroll
      for (int kvt = 0; kvt < 4; ++kvt) {
        u16x4 pw;
#pragma unroll
        for (int r = 0; r < 4; ++r) {
          const float pv = exp2f(s_[kvt][r] - m);
          rs += pv;
          pw[r] = f2b(pv);
        }
        *(u16x4*)&myP[l16 * 72 + kvt * 16 + g * 4] = pw;
      }
      rs += __shfl_xor(rs, 16);
      rs += __shfl_xor(rs, 32);
      l = l * scl + rs;
    }
    bf16v8 pa[2];
#pragma unroll
    for (int kk = 0; kk < 2; ++kk)
      pa[kk] = *(const bf16v8*)&myP[l16 * 72 + kk * 32 + g * 8];
#pragma unroll
    for (int ht = 0; ht < 4; ++ht) {
      po[ht] = mfma16(pa[0], vf[ht][0], po[ht]);
      po[ht] = mfma16(pa[1], vf[ht][1], po[ht]);
    }

    __syncthreads();

    if (s == nchA - 1 || s == total - 1) {
#pragma unroll
      for (int r = 0; r < 4; ++r) {
        const float lr = __shfl(l, g * 4 + r);
        const float inv = 1.f / lr;
        const int qq = qw + g * 4 + r;
#pragma unroll
        for (int ht = 0; ht < 4; ++ht)
          Zh[(size_t)qq * 768 + ht * 16 + l16] = f2b(po[ht][r] * inv);
      }
      m = -3e38f;
      l = 0.f;
#pragma unroll
      for (int ht = 0; ht < 4; ++ht) po[ht] = (f32x4)0.f;
    }
  }
#undef FSTAGE
#undef SWZ
}

// ---------------------------------------------------------------- launch ----
extern "C" void kernel_launch(void* const* d_in, const int* in_sizes, int n_in,
                              void* d_out, int out_size, void* d_ws,
                              size_t ws_size, hipStream_t stream) {
  const float* x  = (const float*)d_in[0];
  const float* wq = (const float*)d_in[1];
  const float* wk = (const float*)d_in[2];
  const float* wv = (const float*)d_in[3];
  const float* wo = (const float*)d_in[4];
  const float* bq = (const float*)d_in[5];
  const float* bk = (const float*)d_in[6];
  const float* bv = (const float*)d_in[7];
  const float* bo = (const float*)d_in[8];
  float* out = (float*)d_out;

  const float sq = 0.18033688011112042f;  // log2(e) / sqrt(64)

  char* ws = (char*)d_ws;
  u16* Xb   = (u16*)ws; ws += 12582912;   // [8192][768] bf16
  u16* BtQK = (u16*)ws; ws += 2359296;    // [1536][768] bf16: WqT*sq | WkT
  u16* WvT  = (u16*)ws; ws += 1179648;    // [768][768]
  u16* WoT  = (u16*)ws; ws += 1179648;    // [768][768]
  float* bc = (float*)ws; ws += 6144;     // [1536] fp32: bq*sq | bk
  u16* QKb  = (u16*)ws; ws += 25165824;   // [8192][1536] (Q | K)
  u16* Vtb  = (u16*)ws; ws += 12582912;   // [768][8192]  (V transposed)
  u16* Zb   = (u16*)ws; ws += 12582912;   // [8192][768]

  // x -> bf16 (+ bias concat in tail blocks)
  pack_x_kernel<<<3078, 256, 0, stream>>>(x, Xb, 786432, bq, bk, bc, sq);
  // all four weights in one launch
  pack_w_all<<<dim3(12, 1, 48), 256, 0, stream>>>(wq, wk, wv, wo, BtQK, WvT,
                                                  WoT, sq);

  // fused Q|K projection: [8192][1536], 768 blocks (3/CU flat)
  gemm_bt<0, 0, 128><<<dim3(64, 12), 256, 0, stream>>>(Xb, BtQK, QKb, bc,
                                                       1.0f, 1536);
  // V^T = (Wv^T) . X^T : A = WvT [768][768], Bt = Xb; 128x64 tiles, 768 blk
  gemm_bt<0, 1, 64><<<dim3(6, 128), 256, 0, stream>>>(WvT, Xb, Vtb, bv, 1.0f,
                                                      8192);

  flash6_kernel<<<dim3(768), 256, 0, stream>>>(QKb, Vtb, Zb);

  // attn-out projection: 128x64 tiles, 768 blocks
  gemm_bt<1, 0, 64><<<dim3(64, 12), 256, 0, stream>>>(Zb, WoT, out, bo, 1.0f,
                                                      768);
}

// Round 10
// 118.538 us; speedup vs baseline: 1.4155x; 1.0095x over previous
//
#include <hip/hip_runtime.h>
#include <stdint.h>

typedef __attribute__((ext_vector_type(4))) float f32x4;
typedef __attribute__((ext_vector_type(8))) __bf16 bf16v8;
typedef __attribute__((ext_vector_type(8))) unsigned short u16x8;
typedef __attribute__((ext_vector_type(4))) unsigned short u16x4;
typedef unsigned short u16;

#define AS1 __attribute__((address_space(1)))
#define AS3 __attribute__((address_space(3)))

__device__ __forceinline__ u16 f2b(float f) {
  union { __bf16 h; u16 u; } c; c.h = (__bf16)f; return c.u;
}

__device__ __forceinline__ f32x4 mfma16(bf16v8 a, bf16v8 b, f32x4 c) {
  return __builtin_amdgcn_mfma_f32_16x16x32_bf16(a, b, c, 0, 0, 0);
}

__device__ __forceinline__ void gl_lds16(const void* g, void* l) {
  __builtin_amdgcn_global_load_lds((AS1 void*)g, (AS3 void*)l, 16, 0, 0);
}

// ------------------------------------------------- pack x (+ bias tail) ----
__global__ __launch_bounds__(256) void pack_x_kernel(
    const float* __restrict__ x, u16* __restrict__ xb, int n8,
    const float* __restrict__ bq, const float* __restrict__ bk,
    float* __restrict__ bc, float sq) {
  int i = blockIdx.x * 256 + threadIdx.x;
  if (i < n8) {
    const f32x4* p = (const f32x4*)(x + (size_t)i * 8);
    f32x4 a = p[0], b = p[1];
    u16x8 o;
    o[0] = f2b(a[0]); o[1] = f2b(a[1]); o[2] = f2b(a[2]); o[3] = f2b(a[3]);
    o[4] = f2b(b[0]); o[5] = f2b(b[1]); o[6] = f2b(b[2]); o[7] = f2b(b[3]);
    *(u16x8*)(xb + (size_t)i * 8) = o;
  } else {
    int j = i - n8;
    if (j < 768) bc[j] = bq[j] * sq;
    else if (j < 1536) bc[j] = bk[j - 768];
  }
}

// --------------------------------------------------- pack all weights ------
__global__ __launch_bounds__(256) void pack_w_all(
    const float* __restrict__ wq, const float* __restrict__ wk,
    const float* __restrict__ wv, const float* __restrict__ wo,
    u16* __restrict__ btqk, u16* __restrict__ wvt, u16* __restrict__ wot,
    float sq) {
  __shared__ float t[64][65];
  const int z = blockIdx.z;
  const int which = z / 12, n = z % 12;
  const int c = threadIdx.x & 63, w = threadIdx.x >> 6;

  const float* in; u16* out; int in_rs, out_ns; float scale;
  int a0, b0;
  if (which == 0) { in = wq; out = btqk;          in_rs = 64;  out_ns = 49152; scale = sq;  }
  else if (which == 1) { in = wk; out = btqk + 589824; in_rs = 64; out_ns = 49152; scale = 1.f; }
  else if (which == 2) { in = wv; out = wvt;      in_rs = 64;  out_ns = 49152; scale = 1.f; }
  else { in = wo; out = wot;                      in_rs = 768; out_ns = 64;    scale = 1.f; }
  if (which < 3) { a0 = blockIdx.x * 64; b0 = 0; }
  else           { a0 = 0; b0 = blockIdx.x * 64; }

  const float* ip = in + (size_t)n * 49152;
#pragma unroll
  for (int i = 0; i < 16; ++i) {
    int r = i * 4 + w;
    t[r][c] = ip[(size_t)(a0 + r) * in_rs + (b0 + c)];
  }
  __syncthreads();
  u16* op = out + (size_t)n * out_ns;
#pragma unroll
  for (int i = 0; i < 16; ++i) {
    int r = i * 4 + w;
    op[(size_t)(b0 + r) * 768 + (a0 + c)] = f2b(t[c][r] * scale);
  }
}

// ------------------------------------------------------------------ GEMM ----
// C[m][col] = (sum_k A[m][k]*Bt[col][k] + bias[BIASROW? m : col]) * scale
// TN=128: 128x128 tile, acc[4][4].  TN=64: 128x64 tile, acc[2][4].
// Grids total 768 blocks -> exactly 3 blocks/CU (flat).
template <int OUTF32, int BIASROW, int TN>
__global__ __launch_bounds__(256, 3) void gemm_bt(
    const u16* __restrict__ A, const u16* __restrict__ Bt,
    void* __restrict__ Cv, const float* __restrict__ bias, float scale, int N) {
  constexpr int K = 768;
  constexpr int MI = (TN == 128) ? 4 : 2;
  __shared__ u16 lA[2][128 * 32];
  __shared__ u16 lB[2][TN * 32];
  constexpr int BBUF = TN * 64;  // bytes per B buffer

  const int tid = threadIdx.x;
  const int lane = tid & 63, wid = tid >> 6;
  const int g = lane >> 4, l16 = lane & 15;
  const int rowb = (TN == 128) ? (wid >> 1) * 64 : wid * 32;
  const int colb = (TN == 128) ? (wid & 1) * 64 : 0;
  const int m0 = blockIdx.x * 128, n0 = blockIdx.y * TN;

  const int srow = tid >> 2;
  const int scol = (tid & 3) * 16;

  f32x4 acc[MI][4];
#pragma unroll
  for (int i = 0; i < MI; ++i)
#pragma unroll
    for (int j = 0; j < 4; ++j) acc[i][j] = (f32x4)0.f;

  const char* Ab = (const char*)(A + (size_t)m0 * K);
  const char* Bb = (const char*)(Bt + (size_t)n0 * K);
  char* lAb = (char*)&lA[0][0];
  char* lBb = (char*)&lB[0][0];

#define STAGE(buf, kt)                                                          \
  do {                                                                          \
    int kb = (kt) * 64;                                                         \
    gl_lds16(Ab + (size_t)srow * 1536 + kb + scol,                              \
             lAb + (buf) * 8192 + wid * 1024);                                  \
    gl_lds16(Ab + (size_t)(64 + srow) * 1536 + kb + scol,                       \
             lAb + (buf) * 8192 + 4096 + wid * 1024);                           \
    if (TN == 128) {                                                            \
      gl_lds16(Bb + (size_t)srow * 1536 + kb + scol,                            \
               lBb + (buf) * BBUF + wid * 1024);                                \
      gl_lds16(Bb + (size_t)(64 + srow) * 1536 + kb + scol,                     \
               lBb + (buf) * BBUF + 4096 + wid * 1024);                         \
    } else if (srow < 64) {                                                     \
      gl_lds16(Bb + (size_t)srow * 1536 + kb + scol,                            \
               lBb + (buf) * BBUF + wid * 1024);                                \
    }                                                                           \
  } while (0)

  STAGE(0, 0);
  __syncthreads();

  for (int kt = 0; kt < 24; ++kt) {
    const int cur = kt & 1;
    if (kt + 1 < 24) STAGE(cur ^ 1, kt + 1);
    bf16v8 af[MI], bfv[4];
#pragma unroll
    for (int i = 0; i < MI; ++i)
      af[i] = *(const bf16v8*)&lA[cur][(rowb + i * 16 + l16) * 32 + g * 8];
#pragma unroll
    for (int j = 0; j < 4; ++j)
      bfv[j] = *(const bf16v8*)&lB[cur][(colb + j * 16 + l16) * 32 + g * 8];
#pragma unroll
    for (int i = 0; i < MI; ++i)
#pragma unroll
      for (int j = 0; j < 4; ++j)
        acc[i][j] = mfma16(af[i], bfv[j], acc[i][j]);
    __syncthreads();
  }
#undef STAGE

  const int row0 = m0 + rowb, col0 = n0 + colb;
#pragma unroll
  for (int j = 0; j < 4; ++j) {
    const int col = col0 + j * 16 + l16;
    const float bcol = BIASROW ? 0.f : bias[col];
#pragma unroll
    for (int i = 0; i < MI; ++i) {
#pragma unroll
      for (int r = 0; r < 4; ++r) {
        const int row = row0 + i * 16 + g * 4 + r;
        const float bv = BIASROW ? bias[row] : bcol;
        const float v = (acc[i][j][r] + bv) * scale;
        if (OUTF32) ((float*)Cv)[(size_t)row * N + col] = v;
        else        ((u16*)Cv)[(size_t)row * N + col] = f2b(v);
      }
    }
  }
}

// ----------------------------------------------------------- flash attn ----
// Structure as R9 (768 flat blocks, 17 chunks each, XCD grouping, swapped
// QK^T, T13 defer-rescale) PLUS T4 counted-vmcnt pipeline: raw s_barrier +
// s_waitcnt vmcnt(4) so the next chunk's 4 global_load_lds stay IN FLIGHT
// across the barrier (no vmcnt(0) drain except final iteration).  Two
// barriers/chunk: (1) staging-of-cur complete, (2) reads done before the
// next-next staging overwrites the buffer.
__global__ __launch_bounds__(256, 3) void flash7_kernel(
    const u16* __restrict__ QK, const u16* __restrict__ Vt,
    u16* __restrict__ Z) {
  __shared__ u16 lK[2][64 * 64];
  __shared__ u16 lV[2][64 * 64];
  __shared__ u16 lP[64 * 72];

  const int tid = threadIdx.x;
  const int lane = tid & 63, wid = tid >> 6;
  const int g = lane >> 4, l16 = lane & 15;

  const int id = blockIdx.x;
  const int xs = id & 7;
  const int rest = id >> 3;       // 0..95
  const int p = rest & 7;         // pair selector 0..7
  const int j = rest >> 3;        // 0..11
  const int head = xs + 8 * j;    // head%8 == xs (XCD grouping)
  const int b = head / 12, n = head % 12;

  const int nchA = 16 - p;        // phase A: half-block 15-p
  const int total = 17;           // + phase B: half-block p (p+1 chunks)

  const u16* Qh = QK + (size_t)b * 1024 * 1536 + n * 64;
  const u16* Kh = Qh + 768;
  const u16* Vh = Vt + (size_t)n * 64 * 8192 + b * 1024;
  u16* Zh = Z + (size_t)b * 1024 * 768 + n * 64;
  u16* myP = &lP[(wid * 16) * 72];   // wave-private 16-row P slice

  const int srow8 = lane >> 3;
  const int sslot = lane & 7;
  const int scol = ((sslot ^ srow8) << 4);

#define FSTAGE(buf, c)                                                        \
  do {                                                                        \
    const int kv0_ = (c) << 6;                                                \
    const char* kb_ = (const char*)Kh + (size_t)(kv0_ + (wid << 4)) * 3072;   \
    const char* vb_ = (const char*)Vh + (size_t)(wid << 4) * 16384 +          \
                      (size_t)kv0_ * 2;                                       \
    gl_lds16(kb_ + (size_t)srow8 * 3072 + scol,                               \
             (char*)&lK[buf][0] + (wid << 11));                               \
    gl_lds16(kb_ + (size_t)(8 + srow8) * 3072 + scol,                         \
             (char*)&lK[buf][0] + (wid << 11) + 1024);                        \
    gl_lds16(vb_ + (size_t)srow8 * 16384 + scol,                              \
             (char*)&lV[buf][0] + (wid << 11));                               \
    gl_lds16(vb_ + (size_t)(8 + srow8) * 16384 + scol,                        \
             (char*)&lV[buf][0] + (wid << 11) + 1024);                        \
  } while (0)

#define SWZ(row, slot) (((row) << 6) + ((((slot) ^ ((row) & 7))) << 3))

  const int qwA = (15 - p) * 64 + wid * 16;
  const int qwB = p * 64 + wid * 16;
  bf16v8 qfA[2], qfB[2];
#pragma unroll
  for (int kk = 0; kk < 2; ++kk) {
    qfA[kk] = *(const bf16v8*)(Qh + (size_t)(qwA + l16) * 1536 + kk * 32 + g * 8);
    qfB[kk] = *(const bf16v8*)(Qh + (size_t)(qwB + l16) * 1536 + kk * 32 + g * 8);
  }

  f32x4 po[4];
#pragma unroll
  for (int ht = 0; ht < 4; ++ht) po[ht] = (f32x4)0.f;
  float m = -3e38f, l = 0.f;

  FSTAGE(0, 0);

  for (int s = 0; s < total; ++s) {
    const int cur = s & 1;
    const bool phB = s >= nchA;
    const int c = phB ? s - nchA : s;
    const int kv0 = c << 6;
    const int qw = phB ? qwB : qwA;

    // issue next chunk's staging, then wait ONLY for current chunk's 4 loads
    // (next 4 stay in flight across the barrier — T4 counted vmcnt)
    if (s + 1 < total) {
      const int s1 = s + 1;
      const int c1 = (s1 >= nchA) ? s1 - nchA : s1;
      FSTAGE(cur ^ 1, c1);
      asm volatile("s_waitcnt vmcnt(4)" ::: "memory");
    } else {
      asm volatile("s_waitcnt vmcnt(0)" ::: "memory");
    }
    __builtin_amdgcn_s_barrier();      // all waves' cur-staging complete
    __builtin_amdgcn_sched_barrier(0);

    const bf16v8 q0 = phB ? qfB[0] : qfA[0];
    const bf16v8 q1 = phB ? qfB[1] : qfA[1];

    bf16v8 kf[4][2];
#pragma unroll
    for (int kvt = 0; kvt < 4; ++kvt)
#pragma unroll
      for (int kk = 0; kk < 2; ++kk)
        kf[kvt][kk] =
            *(const bf16v8*)&lK[cur][SWZ(kvt * 16 + l16, kk * 4 + g)];
    f32x4 s_[4];
#pragma unroll
    for (int kvt = 0; kvt < 4; ++kvt) {
      f32x4 a = (f32x4)0.f;
      a = mfma16(kf[kvt][0], q0, a);
      a = mfma16(kf[kvt][1], q1, a);
      s_[kvt] = a;
    }
    bf16v8 vf[4][2];
#pragma unroll
    for (int ht = 0; ht < 4; ++ht)
#pragma unroll
      for (int kk = 0; kk < 2; ++kk)
        vf[ht][kk] =
            *(const bf16v8*)&lV[cur][SWZ(ht * 16 + l16, kk * 4 + g)];

    if (kv0 + 63 > qw) {  // causal mask: chunk's max kv exceeds wave's min q
      const int qq = qw + l16;
#pragma unroll
      for (int kvt = 0; kvt < 4; ++kvt) {
        const int kv = kv0 + kvt * 16 + g * 4;
#pragma unroll
        for (int r = 0; r < 4; ++r)
          if (kv + r > qq) s_[kvt][r] = -3e38f;
      }
    }
    // online softmax (q-row = l16 lane-local over kv), T13 defer-rescale
    {
      float cm = s_[0][0];
#pragma unroll
      for (int kvt = 0; kvt < 4; ++kvt)
#pragma unroll
        for (int r = 0; r < 4; ++r) cm = fmaxf(cm, s_[kvt][r]);
      cm = fmaxf(cm, __shfl_xor(cm, 16));
      cm = fmaxf(cm, __shfl_xor(cm, 32));
      const bool defer = __all(cm - m <= 8.0f);
      float scl = 1.0f;
      if (!defer) {
        const float mn = fmaxf(m, cm);
        scl = exp2f(m - mn);
        m = mn;
#pragma unroll
        for (int r = 0; r < 4; ++r) {
          const float sr = __shfl(scl, g * 4 + r);
#pragma unroll
          for (int ht = 0; ht < 4; ++ht) po[ht][r] *= sr;
        }
      }
      float rs = 0.f;
#pragma unroll
      for (int kvt = 0; kvt < 4; ++kvt) {
        u16x4 pw;
#pragma unroll
        for (int r = 0; r < 4; ++r) {
          const float pv = exp2f(s_[kvt][r] - m);
          rs += pv;
          pw[r] = f2b(pv);
        }
        *(u16x4*)&myP[l16 * 72 + kvt * 16 + g * 4] = pw;
      }
      rs += __shfl_xor(rs, 16);
      rs += __shfl_xor(rs, 32);
      l = l * scl + rs;
    }
    bf16v8 pa[2];
#pragma unroll
    for (int kk = 0; kk < 2; ++kk)
      pa[kk] = *(const bf16v8*)&myP[l16 * 72 + kk * 32 + g * 8];
#pragma unroll
    for (int ht = 0; ht < 4; ++ht) {
      po[ht] = mfma16(pa[0], vf[ht][0], po[ht]);
      po[ht] = mfma16(pa[1], vf[ht][1], po[ht]);
    }

    __builtin_amdgcn_s_barrier();      // reads done before buffer overwrite

    if (s == nchA - 1 || s == total - 1) {
#pragma unroll
      for (int r = 0; r < 4; ++r) {
        const float lr = __shfl(l, g * 4 + r);
        const float inv = 1.f / lr;
        const int qq = qw + g * 4 + r;
#pragma unroll
        for (int ht = 0; ht < 4; ++ht)
          Zh[(size_t)qq * 768 + ht * 16 + l16] = f2b(po[ht][r] * inv);
      }
      m = -3e38f;
      l = 0.f;
#pragma unroll
      for (int ht = 0; ht < 4; ++ht) po[ht] = (f32x4)0.f;
    }
  }
#undef FSTAGE
#undef SWZ
}

// ---------------------------------------------------------------- launch ----
extern "C" void kernel_launch(void* const* d_in, const int* in_sizes, int n_in,
                              void* d_out, int out_size, void* d_ws,
                              size_t ws_size, hipStream_t stream) {
  const float* x  = (const float*)d_in[0];
  const float* wq = (const float*)d_in[1];
  const float* wk = (const float*)d_in[2];
  const float* wv = (const float*)d_in[3];
  const float* wo = (const float*)d_in[4];
  const float* bq = (const float*)d_in[5];
  const float* bk = (const float*)d_in[6];
  const float* bv = (const float*)d_in[7];
  const float* bo = (const float*)d_in[8];
  float* out = (float*)d_out;

  const float sq = 0.18033688011112042f;  // log2(e) / sqrt(64)

  char* ws = (char*)d_ws;
  u16* Xb   = (u16*)ws; ws += 12582912;   // [8192][768] bf16
  u16* BtQK = (u16*)ws; ws += 2359296;    // [1536][768] bf16: WqT*sq | WkT
  u16* WvT  = (u16*)ws; ws += 1179648;    // [768][768]
  u16* WoT  = (u16*)ws; ws += 1179648;    // [768][768]
  float* bc = (float*)ws; ws += 6144;     // [1536] fp32: bq*sq | bk
  u16* QKb  = (u16*)ws; ws += 25165824;   // [8192][1536] (Q | K)
  u16* Vtb  = (u16*)ws; ws += 12582912;   // [768][8192]  (V transposed)
  u16* Zb   = (u16*)ws; ws += 12582912;   // [8192][768]

  pack_x_kernel<<<3078, 256, 0, stream>>>(x, Xb, 786432, bq, bk, bc, sq);
  pack_w_all<<<dim3(12, 1, 48), 256, 0, stream>>>(wq, wk, wv, wo, BtQK, WvT,
                                                  WoT, sq);

  // fused Q|K projection: [8192][1536], 768 blocks (3/CU flat)
  gemm_bt<0, 0, 128><<<dim3(64, 12), 256, 0, stream>>>(Xb, BtQK, QKb, bc,
                                                       1.0f, 1536);
  // V^T = (Wv^T) . X^T : A = WvT [768][768], Bt = Xb; 128x64 tiles, 768 blk
  gemm_bt<0, 1, 64><<<dim3(6, 128), 256, 0, stream>>>(WvT, Xb, Vtb, bv, 1.0f,
                                                      8192);

  flash7_kernel<<<dim3(768), 256, 0, stream>>>(QKb, Vtb, Zb);

  // attn-out projection: 128x64 tiles, 768 blocks
  gemm_bt<1, 0, 64><<<dim3(64, 12), 256, 0, stream>>>(Zb, WoT, out, bo, 1.0f,
                                                      768);
}

// Round 12
// 106.605 us; speedup vs baseline: 1.5739x; 1.1119x over previous
//
#include <hip/hip_runtime.h>
#include <stdint.h>

typedef __attribute__((ext_vector_type(4))) float f32x4;
typedef __attribute__((ext_vector_type(8))) __bf16 bf16v8;
typedef __attribute__((ext_vector_type(8))) unsigned short u16x8;
typedef __attribute__((ext_vector_type(4))) unsigned short u16x4;
typedef unsigned short u16;

#define AS1 __attribute__((address_space(1)))
#define AS3 __attribute__((address_space(3)))

__device__ __forceinline__ u16 f2b(float f) {
  union { __bf16 h; u16 u; } c; c.h = (__bf16)f; return c.u;
}

__device__ __forceinline__ f32x4 mfma16(bf16v8 a, bf16v8 b, f32x4 c) {
  return __builtin_amdgcn_mfma_f32_16x16x32_bf16(a, b, c, 0, 0, 0);
}

__device__ __forceinline__ void gl_lds16(const void* g, void* l) {
  __builtin_amdgcn_global_load_lds((AS1 void*)g, (AS3 void*)l, 16, 0, 0);
}

// ------------------------------------------------- pack x (+ bias tail) ----
__global__ __launch_bounds__(256) void pack_x_kernel(
    const float* __restrict__ x, u16* __restrict__ xb, int n8,
    const float* __restrict__ bq, const float* __restrict__ bk,
    const float* __restrict__ bv, float* __restrict__ bc, float sq) {
  int i = blockIdx.x * 256 + threadIdx.x;
  if (i < n8) {
    const f32x4* p = (const f32x4*)(x + (size_t)i * 8);
    f32x4 a = p[0], b = p[1];
    u16x8 o;
    o[0] = f2b(a[0]); o[1] = f2b(a[1]); o[2] = f2b(a[2]); o[3] = f2b(a[3]);
    o[4] = f2b(b[0]); o[5] = f2b(b[1]); o[6] = f2b(b[2]); o[7] = f2b(b[3]);
    *(u16x8*)(xb + (size_t)i * 8) = o;
  } else {
    int j = i - n8;
    if (j < 768) bc[j] = bq[j] * sq;
    else if (j < 1536) bc[j] = bk[j - 768];
    else if (j < 2304) bc[j] = bv[j - 1536];
  }
}

// --------------------------------------------------- pack all weights ------
// z = which*12 + n.  which 0: wq*sq -> BtQKV; 1: wk -> +589824;
// 2: wv -> +1179648; 3: wo -> WoT (in_rs 768, b-tiles on blockIdx.x).
__global__ __launch_bounds__(256) void pack_w_all(
    const float* __restrict__ wq, const float* __restrict__ wk,
    const float* __restrict__ wv, const float* __restrict__ wo,
    u16* __restrict__ btqkv, u16* __restrict__ wot, float sq) {
  __shared__ float t[64][65];
  const int z = blockIdx.z;
  const int which = z / 12, n = z % 12;
  const int c = threadIdx.x & 63, w = threadIdx.x >> 6;

  const float* in; u16* out; int in_rs; float scale;
  int a0, b0;
  if (which == 0)      { in = wq; out = btqkv;           in_rs = 64;  scale = sq;  }
  else if (which == 1) { in = wk; out = btqkv + 589824;  in_rs = 64;  scale = 1.f; }
  else if (which == 2) { in = wv; out = btqkv + 1179648; in_rs = 64;  scale = 1.f; }
  else                 { in = wo; out = wot;             in_rs = 768; scale = 1.f; }
  if (which < 3) { a0 = blockIdx.x * 64; b0 = 0; }
  else           { a0 = 0; b0 = blockIdx.x * 64; }

  const float* ip = in + (size_t)n * 49152;
#pragma unroll
  for (int i = 0; i < 16; ++i) {
    int r = i * 4 + w;
    t[r][c] = ip[(size_t)(a0 + r) * in_rs + (b0 + c)];
  }
  __syncthreads();
  u16* op = out + (size_t)n * ((which < 3) ? 49152 : 64);
#pragma unroll
  for (int i = 0; i < 16; ++i) {
    int r = i * 4 + w;
    op[(size_t)(b0 + r) * 768 + (a0 + c)] = f2b(t[c][r] * scale);
  }
}

// ------------------------------------------------- fused QKV projection ----
// A = Xb [8192][768], Bt = [WqT*sq|WkT|WvT] [2304][768].  128x192 tiles,
// grid (64,12) = 768 blocks (3/CU flat).  4 waves = 2x2 of (64 rows x 96
// cols), acc[4][6].  Blocks y<8 (cols<1536) -> QKb[row][col] bf16 (stride
// 1536, Q|K layout flash expects).  Blocks y>=8 -> V, stored TRANSPOSED from
// registers: acc r-values are consecutive Vt rows -> contiguous u16x4 store
// at Vtb[col*8192+row].  Deletes the separate Vt GEMM.
__global__ __launch_bounds__(256, 3) void gemm_qkv(
    const u16* __restrict__ A, const u16* __restrict__ Bt,
    u16* __restrict__ QKb, u16* __restrict__ Vtb,
    const float* __restrict__ bias) {
  __shared__ u16 lA[2][128 * 32];
  __shared__ u16 lB[2][192 * 32];

  const int tid = threadIdx.x;
  const int lane = tid & 63, wid = tid >> 6;
  const int g = lane >> 4, l16 = lane & 15;
  const int wr = wid >> 1, wc = wid & 1;
  const int m0 = blockIdx.x * 128, n0 = blockIdx.y * 192;

  const int srow = tid >> 2;
  const int scol = (tid & 3) * 16;

  f32x4 acc[4][6];
#pragma unroll
  for (int i = 0; i < 4; ++i)
#pragma unroll
    for (int j = 0; j < 6; ++j) acc[i][j] = (f32x4)0.f;

  const char* Ab = (const char*)(A + (size_t)m0 * 768);
  const char* Bb = (const char*)(Bt + (size_t)n0 * 768);
  char* lAb = (char*)&lA[0][0];
  char* lBb = (char*)&lB[0][0];

#define QSTAGE(buf, kt)                                                         \
  do {                                                                          \
    int kb = (kt) * 64;                                                         \
    gl_lds16(Ab + (size_t)srow * 1536 + kb + scol,                              \
             lAb + (buf) * 8192 + wid * 1024);                                  \
    gl_lds16(Ab + (size_t)(64 + srow) * 1536 + kb + scol,                       \
             lAb + (buf) * 8192 + 4096 + wid * 1024);                           \
    gl_lds16(Bb + (size_t)srow * 1536 + kb + scol,                              \
             lBb + (buf) * 12288 + wid * 1024);                                 \
    gl_lds16(Bb + (size_t)(64 + srow) * 1536 + kb + scol,                       \
             lBb + (buf) * 12288 + 4096 + wid * 1024);                          \
    gl_lds16(Bb + (size_t)(128 + srow) * 1536 + kb + scol,                      \
             lBb + (buf) * 12288 + 8192 + wid * 1024);                          \
  } while (0)

  QSTAGE(0, 0);
  __syncthreads();

  for (int kt = 0; kt < 24; ++kt) {
    const int cur = kt & 1;
    if (kt + 1 < 24) QSTAGE(cur ^ 1, kt + 1);
    bf16v8 af[4], bfv[6];
#pragma unroll
    for (int i = 0; i < 4; ++i)
      af[i] = *(const bf16v8*)&lA[cur][(wr * 64 + i * 16 + l16) * 32 + g * 8];
#pragma unroll
    for (int j = 0; j < 6; ++j)
      bfv[j] = *(const bf16v8*)&lB[cur][(wc * 96 + j * 16 + l16) * 32 + g * 8];
#pragma unroll
    for (int i = 0; i < 4; ++i)
#pragma unroll
      for (int j = 0; j < 6; ++j)
        acc[i][j] = mfma16(af[i], bfv[j], acc[i][j]);
    __syncthreads();
  }
#undef QSTAGE

  const int row0 = m0 + wr * 64, col0 = n0 + wc * 96;
  if (n0 < 1536) {  // Q|K part -> QKb[row][col]
#pragma unroll
    for (int j = 0; j < 6; ++j) {
      const int col = col0 + j * 16 + l16;
      const float bcol = bias[col];
#pragma unroll
      for (int i = 0; i < 4; ++i)
#pragma unroll
        for (int r = 0; r < 4; ++r) {
          const int row = row0 + i * 16 + g * 4 + r;
          QKb[(size_t)row * 1536 + col] = f2b(acc[i][j][r] + bcol);
        }
    }
  } else {  // V part -> transposed store into Vtb[col-1536][row]
#pragma unroll
    for (int j = 0; j < 6; ++j) {
      const int col = col0 + j * 16 + l16;
      const float bcol = bias[col];
      const size_t vrow = (size_t)(col - 1536) * 8192;
#pragma unroll
      for (int i = 0; i < 4; ++i) {
        u16x4 pw;
#pragma unroll
        for (int r = 0; r < 4; ++r) pw[r] = f2b(acc[i][j][r] + bcol);
        *(u16x4*)&Vtb[vrow + row0 + i * 16 + g * 4] = pw;
      }
    }
  }
}

// ------------------------------------------------------------------ GEMM ----
// O-projection: C[m][col] = sum_k A[m][k]*Bt[col][k] + bias[col], fp32 out.
// 128x64 tiles, grid (64,12) = 768 blocks (3/CU flat).
__global__ __launch_bounds__(256, 3) void gemm_o(
    const u16* __restrict__ A, const u16* __restrict__ Bt,
    float* __restrict__ C, const float* __restrict__ bias) {
  __shared__ u16 lA[2][128 * 32];
  __shared__ u16 lB[2][64 * 32];

  const int tid = threadIdx.x;
  const int lane = tid & 63, wid = tid >> 6;
  const int g = lane >> 4, l16 = lane & 15;
  const int rowb = wid * 32;
  const int m0 = blockIdx.x * 128, n0 = blockIdx.y * 64;

  const int srow = tid >> 2;
  const int scol = (tid & 3) * 16;

  f32x4 acc[2][4];
#pragma unroll
  for (int i = 0; i < 2; ++i)
#pragma unroll
    for (int j = 0; j < 4; ++j) acc[i][j] = (f32x4)0.f;

  const char* Ab = (const char*)(A + (size_t)m0 * 768);
  const char* Bb = (const char*)(Bt + (size_t)n0 * 768);
  char* lAb = (char*)&lA[0][0];
  char* lBb = (char*)&lB[0][0];

#define OSTAGE(buf, kt)                                                         \
  do {                                                                          \
    int kb = (kt) * 64;                                                         \
    gl_lds16(Ab + (size_t)srow * 1536 + kb + scol,                              \
             lAb + (buf) * 8192 + wid * 1024);                                  \
    gl_lds16(Ab + (size_t)(64 + srow) * 1536 + kb + scol,                       \
             lAb + (buf) * 8192 + 4096 + wid * 1024);                           \
    if (srow < 64)                                                              \
      gl_lds16(Bb + (size_t)srow * 1536 + kb + scol,                            \
               lBb + (buf) * 4096 + wid * 1024);                                \
  } while (0)

  OSTAGE(0, 0);
  __syncthreads();

  for (int kt = 0; kt < 24; ++kt) {
    const int cur = kt & 1;
    if (kt + 1 < 24) OSTAGE(cur ^ 1, kt + 1);
    bf16v8 af[2], bfv[4];
#pragma unroll
    for (int i = 0; i < 2; ++i)
      af[i] = *(const bf16v8*)&lA[cur][(rowb + i * 16 + l16) * 32 + g * 8];
#pragma unroll
    for (int j = 0; j < 4; ++j)
      bfv[j] = *(const bf16v8*)&lB[cur][(j * 16 + l16) * 32 + g * 8];
#pragma unroll
    for (int i = 0; i < 2; ++i)
#pragma unroll
      for (int j = 0; j < 4; ++j)
        acc[i][j] = mfma16(af[i], bfv[j], acc[i][j]);
    __syncthreads();
  }
#undef OSTAGE

  const int row0 = m0 + rowb;
#pragma unroll
  for (int j = 0; j < 4; ++j) {
    const int col = n0 + j * 16 + l16;
    const float bcol = bias[col];
#pragma unroll
    for (int i = 0; i < 2; ++i)
#pragma unroll
      for (int r = 0; r < 4; ++r) {
        const int row = row0 + i * 16 + g * 4 + r;
        C[(size_t)row * 768 + col] = acc[i][j][r] + bcol;
      }
  }
}

// ----------------------------------------------------------- flash attn ----
// (identical to R10's flash7)  768 flat blocks, 17 chunks each, XCD grouping,
// swapped QK^T, T13 defer-rescale, T4 counted-vmcnt double-buffer.
__global__ __launch_bounds__(256, 3) void flash7_kernel(
    const u16* __restrict__ QK, const u16* __restrict__ Vt,
    u16* __restrict__ Z) {
  __shared__ u16 lK[2][64 * 64];
  __shared__ u16 lV[2][64 * 64];
  __shared__ u16 lP[64 * 72];

  const int tid = threadIdx.x;
  const int lane = tid & 63, wid = tid >> 6;
  const int g = lane >> 4, l16 = lane & 15;

  const int id = blockIdx.x;
  const int xs = id & 7;
  const int rest = id >> 3;       // 0..95
  const int p = rest & 7;         // pair selector 0..7
  const int j = rest >> 3;        // 0..11
  const int head = xs + 8 * j;    // head%8 == xs (XCD grouping)
  const int b = head / 12, n = head % 12;

  const int nchA = 16 - p;        // phase A: half-block 15-p
  const int total = 17;           // + phase B: half-block p (p+1 chunks)

  const u16* Qh = QK + (size_t)b * 1024 * 1536 + n * 64;
  const u16* Kh = Qh + 768;
  const u16* Vh = Vt + (size_t)n * 64 * 8192 + b * 1024;
  u16* Zh = Z + (size_t)b * 1024 * 768 + n * 64;
  u16* myP = &lP[(wid * 16) * 72];

  const int srow8 = lane >> 3;
  const int sslot = lane & 7;
  const int scol = ((sslot ^ srow8) << 4);

#define FSTAGE(buf, c)                                                        \
  do {                                                                        \
    const int kv0_ = (c) << 6;                                                \
    const char* kb_ = (const char*)Kh + (size_t)(kv0_ + (wid << 4)) * 3072;   \
    const char* vb_ = (const char*)Vh + (size_t)(wid << 4) * 16384 +          \
                      (size_t)kv0_ * 2;                                       \
    gl_lds16(kb_ + (size_t)srow8 * 3072 + scol,                               \
             (char*)&lK[buf][0] + (wid << 11));                               \
    gl_lds16(kb_ + (size_t)(8 + srow8) * 3072 + scol,                         \
             (char*)&lK[buf][0] + (wid << 11) + 1024);                        \
    gl_lds16(vb_ + (size_t)srow8 * 16384 + scol,                              \
             (char*)&lV[buf][0] + (wid << 11));                               \
    gl_lds16(vb_ + (size_t)(8 + srow8) * 16384 + scol,                        \
             (char*)&lV[buf][0] + (wid << 11) + 1024);                        \
  } while (0)

#define SWZ(row, slot) (((row) << 6) + ((((slot) ^ ((row) & 7))) << 3))

  const int qwA = (15 - p) * 64 + wid * 16;
  const int qwB = p * 64 + wid * 16;
  bf16v8 qfA[2], qfB[2];
#pragma unroll
  for (int kk = 0; kk < 2; ++kk) {
    qfA[kk] = *(const bf16v8*)(Qh + (size_t)(qwA + l16) * 1536 + kk * 32 + g * 8);
    qfB[kk] = *(const bf16v8*)(Qh + (size_t)(qwB + l16) * 1536 + kk * 32 + g * 8);
  }

  f32x4 po[4];
#pragma unroll
  for (int ht = 0; ht < 4; ++ht) po[ht] = (f32x4)0.f;
  float m = -3e38f, l = 0.f;

  FSTAGE(0, 0);

  for (int s = 0; s < total; ++s) {
    const int cur = s & 1;
    const bool phB = s >= nchA;
    const int c = phB ? s - nchA : s;
    const int kv0 = c << 6;
    const int qw = phB ? qwB : qwA;

    if (s + 1 < total) {
      const int s1 = s + 1;
      const int c1 = (s1 >= nchA) ? s1 - nchA : s1;
      FSTAGE(cur ^ 1, c1);
      asm volatile("s_waitcnt vmcnt(4)" ::: "memory");
    } else {
      asm volatile("s_waitcnt vmcnt(0)" ::: "memory");
    }
    __builtin_amdgcn_s_barrier();
    __builtin_amdgcn_sched_barrier(0);

    const bf16v8 q0 = phB ? qfB[0] : qfA[0];
    const bf16v8 q1 = phB ? qfB[1] : qfA[1];

    bf16v8 kf[4][2];
#pragma unroll
    for (int kvt = 0; kvt < 4; ++kvt)
#pragma unroll
      for (int kk = 0; kk < 2; ++kk)
        kf[kvt][kk] =
            *(const bf16v8*)&lK[cur][SWZ(kvt * 16 + l16, kk * 4 + g)];
    f32x4 s_[4];
#pragma unroll
    for (int kvt = 0; kvt < 4; ++kvt) {
      f32x4 a = (f32x4)0.f;
      a = mfma16(kf[kvt][0], q0, a);
      a = mfma16(kf[kvt][1], q1, a);
      s_[kvt] = a;
    }
    bf16v8 vf[4][2];
#pragma unroll
    for (int ht = 0; ht < 4; ++ht)
#pragma unroll
      for (int kk = 0; kk < 2; ++kk)
        vf[ht][kk] =
            *(const bf16v8*)&lV[cur][SWZ(ht * 16 + l16, kk * 4 + g)];

    if (kv0 + 63 > qw) {
      const int qq = qw + l16;
#pragma unroll
      for (int kvt = 0; kvt < 4; ++kvt) {
        const int kv = kv0 + kvt * 16 + g * 4;
#pragma unroll
        for (int r = 0; r < 4; ++r)
          if (kv + r > qq) s_[kvt][r] = -3e38f;
      }
    }
    {
      float cm = s_[0][0];
#pragma unroll
      for (int kvt = 0; kvt < 4; ++kvt)
#pragma unroll
        for (int r = 0; r < 4; ++r) cm = fmaxf(cm, s_[kvt][r]);
      cm = fmaxf(cm, __shfl_xor(cm, 16));
      cm = fmaxf(cm, __shfl_xor(cm, 32));
      const bool defer = __all(cm - m <= 8.0f);
      float scl = 1.0f;
      if (!defer) {
        const float mn = fmaxf(m, cm);
        scl = exp2f(m - mn);
        m = mn;
#pragma unroll
        for (int r = 0; r < 4; ++r) {
          const float sr = __shfl(scl, g * 4 + r);
#pragma unroll
          for (int ht = 0; ht < 4; ++ht) po[ht][r] *= sr;
        }
      }
      float rs = 0.f;
#pragma unroll
      for (int kvt = 0; kvt < 4; ++kvt) {
        u16x4 pw;
#pragma unroll
        for (int r = 0; r < 4; ++r) {
          const float pv = exp2f(s_[kvt][r] - m);
          rs += pv;
          pw[r] = f2b(pv);
        }
        *(u16x4*)&myP[l16 * 72 + kvt * 16 + g * 4] = pw;
      }
      rs += __shfl_xor(rs, 16);
      rs += __shfl_xor(rs, 32);
      l = l * scl + rs;
    }
    bf16v8 pa[2];
#pragma unroll
    for (int kk = 0; kk < 2; ++kk)
      pa[kk] = *(const bf16v8*)&myP[l16 * 72 + kk * 32 + g * 8];
#pragma unroll
    for (int ht = 0; ht < 4; ++ht) {
      po[ht] = mfma16(pa[0], vf[ht][0], po[ht]);
      po[ht] = mfma16(pa[1], vf[ht][1], po[ht]);
    }

    __builtin_amdgcn_s_barrier();

    if (s == nchA - 1 || s == total - 1) {
#pragma unroll
      for (int r = 0; r < 4; ++r) {
        const float lr = __shfl(l, g * 4 + r);
        const float inv = 1.f / lr;
        const int qq = qw + g * 4 + r;
#pragma unroll
        for (int ht = 0; ht < 4; ++ht)
          Zh[(size_t)qq * 768 + ht * 16 + l16] = f2b(po[ht][r] * inv);
      }
      m = -3e38f;
      l = 0.f;
#pragma unroll
      for (int ht = 0; ht < 4; ++ht) po[ht] = (f32x4)0.f;
    }
  }
#undef FSTAGE
#undef SWZ
}

// ---------------------------------------------------------------- launch ----
extern "C" void kernel_launch(void* const* d_in, const int* in_sizes, int n_in,
                              void* d_out, int out_size, void* d_ws,
                              size_t ws_size, hipStream_t stream) {
  const float* x  = (const float*)d_in[0];
  const float* wq = (const float*)d_in[1];
  const float* wk = (const float*)d_in[2];
  const float* wv = (const float*)d_in[3];
  const float* wo = (const float*)d_in[4];
  const float* bq = (const float*)d_in[5];
  const float* bk = (const float*)d_in[6];
  const float* bv = (const float*)d_in[7];
  const float* bo = (const float*)d_in[8];
  float* out = (float*)d_out;

  const float sq = 0.18033688011112042f;  // log2(e) / sqrt(64)

  char* ws = (char*)d_ws;
  u16* Xb    = (u16*)ws; ws += 12582912;  // [8192][768] bf16
  u16* BtQKV = (u16*)ws; ws += 3538944;   // [2304][768] bf16: WqT*sq|WkT|WvT
  u16* WoT   = (u16*)ws; ws += 1179648;   // [768][768]
  float* bc  = (float*)ws; ws += 9216;    // [2304] fp32: bq*sq | bk | bv
  u16* QKb   = (u16*)ws; ws += 25165824;  // [8192][1536] (Q | K)
  u16* Vtb   = (u16*)ws; ws += 12582912;  // [768][8192]  (V transposed)
  u16* Zb    = (u16*)ws; ws += 12582912;  // [8192][768]

  pack_x_kernel<<<3081, 256, 0, stream>>>(x, Xb, 786432, bq, bk, bv, bc, sq);
  pack_w_all<<<dim3(12, 1, 48), 256, 0, stream>>>(wq, wk, wv, wo, BtQKV, WoT,
                                                  sq);

  // fused Q|K|V projection with transposed-V epilogue: 768 blocks (3/CU)
  gemm_qkv<<<dim3(64, 12), 256, 0, stream>>>(Xb, BtQKV, QKb, Vtb, bc);

  flash7_kernel<<<dim3(768), 256, 0, stream>>>(QKb, Vtb, Zb);

  // attn-out projection: 128x64 tiles, 768 blocks
  gemm_o<<<dim3(64, 12), 256, 0, stream>>>(Zb, WoT, out, bo);
}